// Round 13
// baseline (424.056 us; speedup 1.0000x reference)
//
#include <hip/hip_runtime.h>
#include <math.h>

#define FDIM 256
#define CDIM 40
#define ZPAD 64
#define NPAD_TO 128

typedef __attribute__((ext_vector_type(8))) __bf16 bf16x8;
typedef __attribute__((ext_vector_type(4))) float f32x4;
typedef __attribute__((ext_vector_type(8))) ushort u16x8;
typedef __attribute__((ext_vector_type(4))) ushort u16x4;

static inline int cdiv(int a, int b) { return (a + b - 1) / b; }

__device__ __forceinline__ float b2f(ushort u) { return __uint_as_float(((unsigned)u) << 16); }
__device__ __forceinline__ ushort f2bf(float f) {
    unsigned u = __float_as_uint(f);
    unsigned r = (u + 0x7FFFu + ((u >> 16) & 1u)) >> 16;
    return (ushort)r;
}
__device__ __forceinline__ unsigned char f2fp8(float f) {
    int p = __builtin_amdgcn_cvt_pk_fp8_f32(f, f, 0, false);
    return (unsigned char)(p & 0xff);
}

__device__ __forceinline__ void gl_lds16(const void* gsrc, void* ldst) {
    __builtin_amdgcn_global_load_lds((const __attribute__((address_space(1))) unsigned*)gsrc,
                                     (__attribute__((address_space(3))) unsigned*)ldst, 16, 0, 0);
}

#define ACC8(v, w)                                                      \
    {                                                                   \
        auto p0 = __builtin_amdgcn_cvt_pk_f32_fp8((v).x, false);        \
        auto p1 = __builtin_amdgcn_cvt_pk_f32_fp8((v).x, true);         \
        auto p2 = __builtin_amdgcn_cvt_pk_f32_fp8((v).y, false);        \
        auto p3 = __builtin_amdgcn_cvt_pk_f32_fp8((v).y, true);         \
        a[0] += (w) * p0[0]; a[1] += (w) * p0[1];                       \
        a[2] += (w) * p1[0]; a[3] += (w) * p1[1];                       \
        a[4] += (w) * p2[0]; a[5] += (w) * p2[1];                       \
        a[6] += (w) * p3[0]; a[7] += (w) * p3[1];                       \
    }

// ---------------- fused prologue: degree count + x cast(fp8) + weight cast(bf16) ----------------
__global__ __launch_bounds__(256) void k_pro(const int* __restrict__ row,
                                             const int* __restrict__ col,
                                             int* __restrict__ cnt_r,
                                             int* __restrict__ cnt_c, int E,
                                             const float* __restrict__ x, int n4,
                                             const float* __restrict__ s1, const float* __restrict__ d1,
                                             const float* __restrict__ s2, const float* __restrict__ d2,
                                             const float* __restrict__ s3, const float* __restrict__ d3,
                                             unsigned char* __restrict__ xb8,
                                             ushort* __restrict__ wb) {
    int i = blockIdx.x * 256 + threadIdx.x;
    if (i < E) {
        atomicAdd(&cnt_r[row[i]], 1);
        atomicAdd(&cnt_c[col[i]], 1);
        return;
    }
    i -= E;
    if (i < n4) {
        float4 v = ((const float4*)x)[i];
        uchar4 o;
        o.x = f2fp8(v.x); o.y = f2fp8(v.y); o.z = f2fp8(v.z); o.w = f2fp8(v.w);
        ((uchar4*)xb8)[i] = o;
        return;
    }
    int o = i - n4;
    const int BIG = 256 * 256;
    const int SM = 64 * 256;
    if (o >= 4 * BIG + 2 * SM) return;
    float v;
    if (o < BIG) v = s1[o];
    else if (o < 2 * BIG) v = d1[o - BIG];
    else if (o < 3 * BIG) v = s2[o - 2 * BIG];
    else if (o < 4 * BIG) v = d2[o - 3 * BIG];
    else {
        int oo = o - 4 * BIG;
        const float* src = (oo < SM) ? s3 : d3;
        oo = (oo < SM) ? oo : oo - SM;
        int r = oo >> 8;
        v = (r < CDIM) ? src[(r << 8) + (oo & 255)] : 0.0f;
    }
    wb[o] = f2bf(v);
}

// ---------------- fused r/c scan ----------------
__global__ __launch_bounds__(256) void k_scan1(const int* __restrict__ cnt_r,
                                               const int* __restrict__ cnt_c,
                                               int* __restrict__ rptr,
                                               int* __restrict__ cptr,
                                               int* __restrict__ bsum, int n) {
    const int* cnt = blockIdx.y ? cnt_c : cnt_r;
    int* ptr = blockIdx.y ? cptr : rptr;
    __shared__ int s[256];
    int t = threadIdx.x;
    int i = blockIdx.x * 256 + t;
    int v = (i < n) ? cnt[i] : 0;
    s[t] = v;
    __syncthreads();
    for (int off = 1; off < 256; off <<= 1) {
        int u = (t >= off) ? s[t - off] : 0;
        __syncthreads();
        s[t] += u;
        __syncthreads();
    }
    if (i < n) ptr[i] = s[t] - v;
    if (t == 255) bsum[blockIdx.y * 256 + blockIdx.x] = s[255];
}

__global__ __launch_bounds__(256) void k_scan2(int* __restrict__ bsum, int nb) {
    int* b = bsum + blockIdx.x * 256;
    __shared__ int s[256];
    int t = threadIdx.x;
    int v = (t < nb) ? b[t] : 0;
    s[t] = v;
    __syncthreads();
    for (int off = 1; off < 256; off <<= 1) {
        int u = (t >= off) ? s[t - off] : 0;
        __syncthreads();
        s[t] += u;
        __syncthreads();
    }
    if (t < nb) b[t] = s[t] - v;
}

// scan3 + inv tables
__global__ __launch_bounds__(256) void k_scan3(int* __restrict__ rptr,
                                               int* __restrict__ cptr,
                                               const int* __restrict__ bsum,
                                               const int* __restrict__ cnt_r,
                                               const int* __restrict__ cnt_c,
                                               float* __restrict__ inv_out,
                                               float* __restrict__ inv_in,
                                               int n, int total) {
    int i = blockIdx.x * 256 + threadIdx.x;
    if (blockIdx.y == 0) {
        if (i < n) {
            rptr[i] += bsum[blockIdx.x];
            int cv = cnt_r[i];
            inv_out[i] = cv > 0 ? rsqrtf((float)cv) : 0.0f;
        }
        if (blockIdx.x == 0 && threadIdx.x == 0) rptr[n] = total;
    } else {
        if (i < n) {
            cptr[i] += bsum[256 + blockIdx.x];
            int cv = cnt_c[i];
            inv_in[i] = cv > 0 ? rsqrtf((float)cv) : 0.0f;
        }
        if (blockIdx.x == 0 && threadIdx.x == 0) cptr[n] = total;
    }
}

// ---------------- direct fill: index-only (4B) adjacency, both directions ----------------
__global__ __launch_bounds__(256) void k_fill(const int* __restrict__ row,
                                              const int* __restrict__ col,
                                              const int* __restrict__ rptr,
                                              const int* __restrict__ cptr,
                                              int* __restrict__ fr, int* __restrict__ fc,
                                              int* __restrict__ nbr_r,
                                              int* __restrict__ nbr_c,
                                              int E) {
    int e = blockIdx.x * 256 + threadIdx.x;
    if (e >= E) return;
    int r = row[e], c = col[e];
    int p = rptr[r] + atomicAdd(&fr[r], 1);
    nbr_r[p] = c;
    int q = cptr[c] + atomicAdd(&fc[c], 1);
    nbr_c[q] = r;
}

// ---------------- fp8 gather: index-only adjacency + inv-table weights ----------------
__global__ __launch_bounds__(256) void k_gather_f8(const unsigned char* __restrict__ h8,
                                                   const int* __restrict__ rptr,
                                                   const int* __restrict__ nbr_r,
                                                   const int* __restrict__ cptr,
                                                   const int* __restrict__ nbr_c,
                                                   const float* __restrict__ inv_out,
                                                   const float* __restrict__ inv_in,
                                                   ushort* __restrict__ agg,
                                                   ushort* __restrict__ aggt, int N) {
    int wv = threadIdx.x >> 6, lane = threadIdx.x & 63;
    int half = lane >> 5, l32 = lane & 31;
    int n = blockIdx.x * 4 + wv;
    if (n >= N) return;
    const int* ptr;
    const int* nbr;
    const float* invt;
    float fac;
    ushort* out;
    if (blockIdx.y == 0) { ptr = rptr; nbr = nbr_r; invt = inv_in; fac = inv_out[n]; out = agg; }
    else                 { ptr = cptr; nbr = nbr_c; invt = inv_out; fac = inv_in[n]; out = aggt; }
    int s = ptr[n], t = ptr[n + 1];
    float a[8] = {};
    for (int base = s; base < t; base += 64) {
        int cnt = t - base;
        if (cnt > 64) cnt = 64;
        int idx = 0;
        float ww = 0.f;
        if (lane < cnt) {
            idx = nbr[base + lane];
            ww = invt[idx];
        }
        for (int i = 0; i < cnt; i += 8) {
            int n0 = i + half, n1 = i + 2 + half, n2 = i + 4 + half, n3 = i + 6 + half;
            int c0 = __shfl(idx, n0, 64); float w0 = __shfl(ww, n0, 64);
            int c1 = __shfl(idx, n1, 64); float w1 = __shfl(ww, n1, 64);
            int c2 = __shfl(idx, n2, 64); float w2 = __shfl(ww, n2, 64);
            int c3 = __shfl(idx, n3, 64); float w3 = __shfl(ww, n3, 64);
            uint2 v0 = ((const uint2*)(h8 + (size_t)c0 * FDIM))[l32];
            uint2 v1 = ((const uint2*)(h8 + (size_t)c1 * FDIM))[l32];
            uint2 v2 = ((const uint2*)(h8 + (size_t)c2 * FDIM))[l32];
            uint2 v3 = ((const uint2*)(h8 + (size_t)c3 * FDIM))[l32];
            ACC8(v0, w0);
            ACC8(v1, w1);
            ACC8(v2, w2);
            ACC8(v3, w3);
        }
    }
#pragma unroll
    for (int j = 0; j < 8; ++j) a[j] += __shfl_xor(a[j], 32, 64);
    if (half == 0) {
        u16x8 o;
#pragma unroll
        for (int j = 0; j < 8; ++j) o[j] = f2bf(a[j] * fac);
        ((u16x8*)(out + (size_t)n * FDIM))[l32] = o;
    }
}

// ---------------- MFMA dual GEMM layers 1-2: BM=64 x BN=128, dual-format epilogue ----------------
__global__ __launch_bounds__(256) void k_gemm12(const ushort* __restrict__ Ab,
                                                const ushort* __restrict__ Atb,
                                                const ushort* __restrict__ Wsb,
                                                const ushort* __restrict__ Wdb,
                                                const float* __restrict__ bs,
                                                const float* __restrict__ bd,
                                                ushort* __restrict__ outH,
                                                unsigned char* __restrict__ out8) {
    __shared__ char smA[8192];
    __shared__ char smAt[8192];
    __shared__ char smWs[16384];
    __shared__ char smWd[16384];

    const int tid = threadIdx.x;
    const int wv = tid >> 6, lane = tid & 63;
    const int n0 = blockIdx.x * 64;
    const int j0 = blockIdx.y * 128;

    const char* Abase = (const char*)Ab;
    const char* Atbase = (const char*)Atb;
    const char* Wsbase = (const char*)Wsb;
    const char* Wdbase = (const char*)Wdb;

    f32x4 accS[8] = {};
    f32x4 accD[8] = {};

    for (int k0 = 0; k0 < FDIM; k0 += 64) {
#pragma unroll
        for (int it = 0; it < 2; ++it) {
            int si = it * 256 + tid;
            int r = si >> 3, sl = si & 7;
            int gs = sl ^ (r & 7);
            size_t goff = (size_t)(n0 + r) * (FDIM * 2) + k0 * 2 + gs * 16;
            gl_lds16(Abase + goff, smA + si * 16);
            gl_lds16(Atbase + goff, smAt + si * 16);
        }
#pragma unroll
        for (int it = 0; it < 4; ++it) {
            int si = it * 256 + tid;
            int r = si >> 3, sl = si & 7;
            int gs = sl ^ (r & 7);
            size_t goff = (size_t)(j0 + r) * (FDIM * 2) + k0 * 2 + gs * 16;
            gl_lds16(Wsbase + goff, smWs + si * 16);
            gl_lds16(Wdbase + goff, smWd + si * 16);
        }
        __syncthreads();
#pragma unroll
        for (int kh = 0; kh < 2; ++kh) {
            int rA = wv * 16 + (lane & 15);
            int sA = (kh * 4 + (lane >> 4)) ^ (rA & 7);
            bf16x8 aS = *(const bf16x8*)(smA + rA * 128 + sA * 16);
            bf16x8 aT = *(const bf16x8*)(smAt + rA * 128 + sA * 16);
#pragma unroll
            for (int ni = 0; ni < 8; ++ni) {
                int rB = ni * 16 + (lane & 15);
                int sB = (kh * 4 + (lane >> 4)) ^ (rB & 7);
                bf16x8 bSv = *(const bf16x8*)(smWs + rB * 128 + sB * 16);
                bf16x8 bDv = *(const bf16x8*)(smWd + rB * 128 + sB * 16);
                accS[ni] = __builtin_amdgcn_mfma_f32_16x16x32_bf16(aS, bSv, accS[ni], 0, 0, 0);
                accD[ni] = __builtin_amdgcn_mfma_f32_16x16x32_bf16(aT, bDv, accD[ni], 0, 0, 0);
            }
        }
        __syncthreads();
    }

#pragma unroll
    for (int ni = 0; ni < 8; ++ni) {
        int j = j0 + ni * 16 + (lane & 15);
        float bsv = bs[j], bdv = bd[j];
#pragma unroll
        for (int r = 0; r < 4; ++r) {
            int n = n0 + wv * 16 + (lane >> 4) * 4 + r;
            float v = 0.5f * (accS[ni][r] + bsv) + 0.5f * (accD[ni][r] + bdv);
            v = fmaxf(v, 0.0f);
            if (out8) out8[(size_t)n * FDIM + j] = f2fp8(v);
            else outH[(size_t)n * FDIM + j] = f2bf(v);
        }
    }
}

// ---------------- MFMA layer-3 GEMM: zs/zd as bf16 padded to 64 cols ----------------
__global__ __launch_bounds__(256) void k_gemm3(const ushort* __restrict__ Hb,
                                               const ushort* __restrict__ Wsb,
                                               const ushort* __restrict__ Wdb,
                                               ushort* __restrict__ zsb,
                                               ushort* __restrict__ zdb) {
    __shared__ char smA[16384];
    __shared__ char smWs[8192];
    __shared__ char smWd[8192];

    const int tid = threadIdx.x;
    const int wv = tid >> 6, lane = tid & 63;
    const int n0 = blockIdx.x * 128;

    const char* Abase = (const char*)Hb;
    const char* Wsbase = (const char*)Wsb;
    const char* Wdbase = (const char*)Wdb;

    f32x4 accS[2][4] = {};
    f32x4 accD[2][4] = {};

    for (int k0 = 0; k0 < FDIM; k0 += 64) {
#pragma unroll
        for (int it = 0; it < 4; ++it) {
            int si = (wv * 4 + it) * 64 + lane;
            int r = si >> 3, sl = si & 7;
            int gs = sl ^ (r & 7);
            size_t goff = (size_t)(n0 + r) * (FDIM * 2) + k0 * 2 + gs * 16;
            gl_lds16(Abase + goff, smA + si * 16);
        }
#pragma unroll
        for (int it = 0; it < 2; ++it) {
            int si = (wv * 2 + it) * 64 + lane;
            int r = si >> 3, sl = si & 7;
            int gs = sl ^ (r & 7);
            size_t goff = (size_t)r * (FDIM * 2) + k0 * 2 + gs * 16;
            gl_lds16(Wsbase + goff, smWs + si * 16);
            gl_lds16(Wdbase + goff, smWd + si * 16);
        }
        __syncthreads();
#pragma unroll
        for (int kh = 0; kh < 2; ++kh) {
            bf16x8 aS[2], bS[4], bD[4];
#pragma unroll
            for (int mi = 0; mi < 2; ++mi) {
                int r = wv * 32 + mi * 16 + (lane & 15);
                int off = r * 128 + (((kh * 4 + (lane >> 4)) ^ (r & 7)) * 16);
                aS[mi] = *(const bf16x8*)(smA + off);
            }
#pragma unroll
            for (int ni = 0; ni < 4; ++ni) {
                int r = ni * 16 + (lane & 15);
                int off = r * 128 + (((kh * 4 + (lane >> 4)) ^ (r & 7)) * 16);
                bS[ni] = *(const bf16x8*)(smWs + off);
                bD[ni] = *(const bf16x8*)(smWd + off);
            }
#pragma unroll
            for (int mi = 0; mi < 2; ++mi)
#pragma unroll
                for (int ni = 0; ni < 4; ++ni) {
                    accS[mi][ni] = __builtin_amdgcn_mfma_f32_16x16x32_bf16(aS[mi], bS[ni], accS[mi][ni], 0, 0, 0);
                    accD[mi][ni] = __builtin_amdgcn_mfma_f32_16x16x32_bf16(aS[mi], bD[ni], accD[mi][ni], 0, 0, 0);
                }
        }
        __syncthreads();
    }

#pragma unroll
    for (int mi = 0; mi < 2; ++mi)
#pragma unroll
        for (int ni = 0; ni < 4; ++ni) {
            int j = ni * 16 + (lane & 15);
            f32x4 cs = accS[mi][ni], cd = accD[mi][ni];
#pragma unroll
            for (int r = 0; r < 4; ++r) {
                int n = n0 + wv * 32 + mi * 16 + (lane >> 4) * 4 + r;
                zsb[(size_t)n * ZPAD + j] = f2bf(cs[r]);
                zdb[(size_t)n * ZPAD + j] = f2bf(cd[r]);
            }
        }
}

// ---------------- layer 3: gather over padded-64 bf16 z + inv-table weights + log_softmax ----------------
__global__ __launch_bounds__(256) void k_l3(const ushort* __restrict__ zsb,
                                            const ushort* __restrict__ zdb,
                                            const int* __restrict__ rptr,
                                            const int* __restrict__ nbr_r,
                                            const int* __restrict__ cptr,
                                            const int* __restrict__ nbr_c,
                                            const float* __restrict__ inv_out,
                                            const float* __restrict__ inv_in,
                                            const float* __restrict__ bs,
                                            const float* __restrict__ bd,
                                            float* __restrict__ out, int N) {
    int wv = threadIdx.x >> 6, lane = threadIdx.x & 63;
    int grp = lane >> 4, sl = lane & 15;
    int n = blockIdx.x * 4 + wv;
    if (n >= N) return;
    float acc[2][4] = {};

#pragma unroll
    for (int dir = 0; dir < 2; ++dir) {
        const int* ptr = dir == 0 ? rptr : cptr;
        const int* nbr = dir == 0 ? nbr_r : nbr_c;
        const float* invt = dir == 0 ? inv_in : inv_out;
        const ushort* zb = dir == 0 ? zsb : zdb;
        int s = ptr[n], t = ptr[n + 1];
        for (int base = s; base < t; base += 64) {
            int cnt = t - base;
            if (cnt > 64) cnt = 64;
            int idx = 0;
            float ww = 0.f;
            if (lane < cnt) {
                idx = nbr[base + lane];
                ww = invt[idx];
            }
            for (int i = 0; i < cnt; i += 8) {
                int n0 = i + grp, n1 = i + 4 + grp;
                int c0 = __shfl(idx, n0, 64); float w0 = __shfl(ww, n0, 64);
                int c1 = __shfl(idx, n1, 64); float w1 = __shfl(ww, n1, 64);
                u16x4 v0 = ((const u16x4*)(zb + (size_t)c0 * ZPAD))[sl];
                u16x4 v1 = ((const u16x4*)(zb + (size_t)c1 * ZPAD))[sl];
#pragma unroll
                for (int j = 0; j < 4; ++j)
                    acc[dir][j] += w0 * b2f(v0[j]) + w1 * b2f(v1[j]);
            }
        }
    }

    float fac0 = 0.5f * inv_out[n], fac1 = 0.5f * inv_in[n];
    float a[4];
#pragma unroll
    for (int j = 0; j < 4; ++j) {
        a[j] = fac0 * acc[0][j] + fac1 * acc[1][j];
        a[j] += __shfl_xor(a[j], 16, 64);
        a[j] += __shfl_xor(a[j], 32, 64);
    }
    float val[4];
#pragma unroll
    for (int j = 0; j < 4; ++j) {
        int c = 4 * sl + j;
        val[j] = (c < CDIM) ? a[j] + 0.5f * (bs[c] + bd[c]) : -INFINITY;
    }
    float m = fmaxf(fmaxf(val[0], val[1]), fmaxf(val[2], val[3]));
    for (int off = 1; off < 16; off <<= 1) m = fmaxf(m, __shfl_xor(m, off, 64));
    float ex = 0.f;
#pragma unroll
    for (int j = 0; j < 4; ++j) ex += (4 * sl + j < CDIM) ? expf(val[j] - m) : 0.f;
    for (int off = 1; off < 16; off <<= 1) ex += __shfl_xor(ex, off, 64);
    float lse = logf(ex);
    if (grp == 0 && sl < 10) {
        float4 o;
        o.x = val[0] - m - lse;
        o.y = val[1] - m - lse;
        o.z = val[2] - m - lse;
        o.w = val[3] - m - lse;
        ((float4*)(out + (size_t)n * CDIM))[sl] = o;
    }
}

extern "C" void kernel_launch(void* const* d_in, const int* in_sizes, int n_in,
                              void* d_out, int out_size, void* d_ws, size_t ws_size,
                              hipStream_t stream) {
    const int N = in_sizes[0] / FDIM;
    const int E = in_sizes[1] / 2;
    const int NP = cdiv(N, NPAD_TO) * NPAD_TO;

    const float* x = (const float*)d_in[0];
    const int* ei = (const int*)d_in[1];
    const int* row = ei;
    const int* col = ei + E;
    const float* ws1 = (const float*)d_in[2];
    const float* bs1 = (const float*)d_in[3];
    const float* wd1 = (const float*)d_in[4];
    const float* bd1 = (const float*)d_in[5];
    const float* ws2 = (const float*)d_in[6];
    const float* bs2 = (const float*)d_in[7];
    const float* wd2 = (const float*)d_in[8];
    const float* bd2 = (const float*)d_in[9];
    const float* ws3 = (const float*)d_in[10];
    const float* bs3 = (const float*)d_in[11];
    const float* wd3 = (const float*)d_in[12];
    const float* bd3 = (const float*)d_in[13];
    float* out = (float*)d_out;

    // ---- workspace carve ----
    char* base = (char*)d_ws;
    int* cnt_r = (int*)base;        base += sizeof(int) * N;
    int* cnt_c = (int*)base;        base += sizeof(int) * N;
    int* fr = (int*)base;           base += sizeof(int) * N;
    int* fc = (int*)base;           base += sizeof(int) * N;
    int* rptr = (int*)base;         base += sizeof(int) * (N + 1);
    int* cptr = (int*)base;         base += sizeof(int) * (N + 1);
    int* bsum = (int*)base;         base += sizeof(int) * 512;
    float* inv_out = (float*)base;  base += sizeof(float) * N;
    float* inv_in = (float*)base;   base += sizeof(float) * N;
    base = (char*)(((size_t)base + 15) & ~(size_t)15);
    int* nbr_r = (int*)base;        base += sizeof(int) * E;
    int* nbr_c = (int*)base;        base += sizeof(int) * E;
    base = (char*)(((size_t)base + 255) & ~(size_t)255);
    unsigned char* xb8 = (unsigned char*)base;  base += (size_t)NP * FDIM;
    base = (char*)(((size_t)base + 255) & ~(size_t)255);
    unsigned char* hb8 = (unsigned char*)base;  base += (size_t)NP * FDIM;
    base = (char*)(((size_t)base + 255) & ~(size_t)255);
    ushort* hb = (ushort*)base;     base += sizeof(ushort) * (size_t)NP * FDIM;
    ushort* aggb = (ushort*)base;   base += sizeof(ushort) * (size_t)NP * FDIM;
    ushort* aggtb = (ushort*)base;  base += sizeof(ushort) * (size_t)NP * FDIM;
    ushort* wbuf = (ushort*)base;   base += sizeof(ushort) * (4 * 65536 + 2 * 16384);
    ushort* zsb = aggb;
    ushort* zdb = aggtb;

    ushort* w1s = wbuf;
    ushort* w1d = wbuf + 65536;
    ushort* w2s = wbuf + 2 * 65536;
    ushort* w2d = wbuf + 3 * 65536;
    ushort* w3s = wbuf + 4 * 65536;
    ushort* w3d = wbuf + 4 * 65536 + 16384;

    const int nb = cdiv(N, 256);
    const int n4 = N * FDIM / 4;
    const int wn = 4 * 65536 + 2 * 16384;

    // ---- prologue: zero counters, count + casts ----
    hipMemsetAsync(cnt_r, 0, sizeof(int) * 4 * (size_t)N, stream);  // cnt_r,cnt_c,fr,fc
    k_pro<<<cdiv(E + n4 + wn, 256), 256, 0, stream>>>(row, col, cnt_r, cnt_c, E,
                                                      x, n4, ws1, wd1, ws2, wd2, ws3, wd3,
                                                      xb8, wbuf);
    k_scan1<<<dim3(nb, 2), 256, 0, stream>>>(cnt_r, cnt_c, rptr, cptr, bsum, N);
    k_scan2<<<2, 256, 0, stream>>>(bsum, nb);
    k_scan3<<<dim3(nb, 2), 256, 0, stream>>>(rptr, cptr, bsum, cnt_r, cnt_c, inv_out, inv_in, N, E);
    k_fill<<<cdiv(E, 256), 256, 0, stream>>>(row, col, rptr, cptr, fr, fc, nbr_r, nbr_c, E);

    dim3 ggrid(cdiv(N, 4), 2);
    dim3 ggemm(NP / 64, 2);
    dim3 ggemm3(NP / 128, 1);

    // layer 1: gather(fp8 x) -> bf16 agg -> GEMM -> fp8 h
    k_gather_f8<<<ggrid, 256, 0, stream>>>(xb8, rptr, nbr_r, cptr, nbr_c, inv_out, inv_in, aggb, aggtb, N);
    k_gemm12<<<ggemm, 256, 0, stream>>>(aggb, aggtb, w1s, w1d, bs1, bd1, nullptr, hb8);

    // layer 2: gather(fp8 h) -> bf16 agg -> GEMM -> bf16 h (for gemm3)
    k_gather_f8<<<ggrid, 256, 0, stream>>>(hb8, rptr, nbr_r, cptr, nbr_c, inv_out, inv_in, aggb, aggtb, N);
    k_gemm12<<<ggemm, 256, 0, stream>>>(aggb, aggtb, w2s, w2d, bs2, bd2, hb, nullptr);

    // layer 3
    k_gemm3<<<ggemm3, 256, 0, stream>>>(hb, w3s, w3d, zsb, zdb);
    k_l3<<<cdiv(N, 4), 256, 0, stream>>>(zsb, zdb, rptr, nbr_r, cptr, nbr_c, inv_out, inv_in,
                                         bs3, bd3, out, N);
}

// Round 14
// 392.991 us; speedup vs baseline: 1.0790x; 1.0790x over previous
//
#include <hip/hip_runtime.h>
#include <math.h>

#define FDIM 256
#define CDIM 40
#define ZPAD 64
#define NPAD_TO 128
#define NPART 16
#define BLKS_PER_PART 64

typedef __attribute__((ext_vector_type(8))) __bf16 bf16x8;
typedef __attribute__((ext_vector_type(4))) float f32x4;
typedef __attribute__((ext_vector_type(8))) ushort u16x8;
typedef __attribute__((ext_vector_type(4))) ushort u16x4;

static inline int cdiv(int a, int b) { return (a + b - 1) / b; }

__device__ __forceinline__ float b2f(ushort u) { return __uint_as_float(((unsigned)u) << 16); }
__device__ __forceinline__ ushort f2bf(float f) {
    unsigned u = __float_as_uint(f);
    unsigned r = (u + 0x7FFFu + ((u >> 16) & 1u)) >> 16;
    return (ushort)r;
}
__device__ __forceinline__ unsigned char f2fp8(float f) {
    int p = __builtin_amdgcn_cvt_pk_fp8_f32(f, f, 0, false);
    return (unsigned char)(p & 0xff);
}

__device__ __forceinline__ void gl_lds16(const void* gsrc, void* ldst) {
    __builtin_amdgcn_global_load_lds((const __attribute__((address_space(1))) unsigned*)gsrc,
                                     (__attribute__((address_space(3))) unsigned*)ldst, 16, 0, 0);
}

#define ACC8(v, w)                                                      \
    {                                                                   \
        auto p0 = __builtin_amdgcn_cvt_pk_f32_fp8((v).x, false);        \
        auto p1 = __builtin_amdgcn_cvt_pk_f32_fp8((v).x, true);         \
        auto p2 = __builtin_amdgcn_cvt_pk_f32_fp8((v).y, false);        \
        auto p3 = __builtin_amdgcn_cvt_pk_f32_fp8((v).y, true);         \
        a[0] += (w) * p0[0]; a[1] += (w) * p0[1];                       \
        a[2] += (w) * p1[0]; a[3] += (w) * p1[1];                       \
        a[4] += (w) * p2[0]; a[5] += (w) * p2[1];                       \
        a[6] += (w) * p3[0]; a[7] += (w) * p3[1];                       \
    }

// ---------------- fused prologue: degree count + x cast(fp8) + weight cast(bf16) ----------------
__global__ __launch_bounds__(256) void k_pro(const int* __restrict__ row,
                                             const int* __restrict__ col,
                                             int* __restrict__ cnt_r,
                                             int* __restrict__ cnt_c, int E,
                                             const float* __restrict__ x, int n4,
                                             const float* __restrict__ s1, const float* __restrict__ d1,
                                             const float* __restrict__ s2, const float* __restrict__ d2,
                                             const float* __restrict__ s3, const float* __restrict__ d3,
                                             unsigned char* __restrict__ xb8,
                                             ushort* __restrict__ wb) {
    int i = blockIdx.x * 256 + threadIdx.x;
    if (i < E) {
        atomicAdd(&cnt_r[row[i]], 1);
        atomicAdd(&cnt_c[col[i]], 1);
        return;
    }
    i -= E;
    if (i < n4) {
        float4 v = ((const float4*)x)[i];
        uchar4 o;
        o.x = f2fp8(v.x); o.y = f2fp8(v.y); o.z = f2fp8(v.z); o.w = f2fp8(v.w);
        ((uchar4*)xb8)[i] = o;
        return;
    }
    int o = i - n4;
    const int BIG = 256 * 256;
    const int SM = 64 * 256;
    if (o >= 4 * BIG + 2 * SM) return;
    float v;
    if (o < BIG) v = s1[o];
    else if (o < 2 * BIG) v = d1[o - BIG];
    else if (o < 3 * BIG) v = s2[o - 2 * BIG];
    else if (o < 4 * BIG) v = d2[o - 3 * BIG];
    else {
        int oo = o - 4 * BIG;
        const float* src = (oo < SM) ? s3 : d3;
        oo = (oo < SM) ? oo : oo - SM;
        int r = oo >> 8;
        v = (r < CDIM) ? src[(r << 8) + (oo & 255)] : 0.0f;
    }
    wb[o] = f2bf(v);
}

// ---------------- fused r/c scan ----------------
__global__ __launch_bounds__(256) void k_scan1(const int* __restrict__ cnt_r,
                                               const int* __restrict__ cnt_c,
                                               int* __restrict__ rptr,
                                               int* __restrict__ cptr,
                                               int* __restrict__ bsum, int n) {
    const int* cnt = blockIdx.y ? cnt_c : cnt_r;
    int* ptr = blockIdx.y ? cptr : rptr;
    __shared__ int s[256];
    int t = threadIdx.x;
    int i = blockIdx.x * 256 + t;
    int v = (i < n) ? cnt[i] : 0;
    s[t] = v;
    __syncthreads();
    for (int off = 1; off < 256; off <<= 1) {
        int u = (t >= off) ? s[t - off] : 0;
        __syncthreads();
        s[t] += u;
        __syncthreads();
    }
    if (i < n) ptr[i] = s[t] - v;
    if (t == 255) bsum[blockIdx.y * 256 + blockIdx.x] = s[255];
}

__global__ __launch_bounds__(256) void k_scan2(int* __restrict__ bsum, int nb) {
    int* b = bsum + blockIdx.x * 256;
    __shared__ int s[256];
    int t = threadIdx.x;
    int v = (t < nb) ? b[t] : 0;
    s[t] = v;
    __syncthreads();
    for (int off = 1; off < 256; off <<= 1) {
        int u = (t >= off) ? s[t - off] : 0;
        __syncthreads();
        s[t] += u;
        __syncthreads();
    }
    if (t < nb) b[t] = s[t] - v;
}

// scan3 + inv tables
__global__ __launch_bounds__(256) void k_scan3(int* __restrict__ rptr,
                                               int* __restrict__ cptr,
                                               const int* __restrict__ bsum,
                                               const int* __restrict__ cnt_r,
                                               const int* __restrict__ cnt_c,
                                               float* __restrict__ inv_out,
                                               float* __restrict__ inv_in,
                                               int n, int total) {
    int i = blockIdx.x * 256 + threadIdx.x;
    if (blockIdx.y == 0) {
        if (i < n) {
            rptr[i] += bsum[blockIdx.x];
            int cv = cnt_r[i];
            inv_out[i] = cv > 0 ? rsqrtf((float)cv) : 0.0f;
        }
        if (blockIdx.x == 0 && threadIdx.x == 0) rptr[n] = total;
    } else {
        if (i < n) {
            cptr[i] += bsum[256 + blockIdx.x];
            int cv = cnt_c[i];
            inv_in[i] = cv > 0 ? rsqrtf((float)cv) : 0.0f;
        }
        if (blockIdx.x == 0 && threadIdx.x == 0) cptr[n] = total;
    }
}

// ---------------- XCD-partitioned fill: each (part,dir) group owns a row range ----------------
// part = blockIdx.x & 15 -> fixed bid%8 -> same XCD for all blocks of a part (round-robin
// dispatch heuristic; correctness does not depend on it). Writes + counters stay XCD-local.
__global__ __launch_bounds__(256) void k_fillp(const int* __restrict__ row,
                                               const int* __restrict__ col,
                                               const int* __restrict__ rptr,
                                               const int* __restrict__ cptr,
                                               int* __restrict__ fr, int* __restrict__ fc,
                                               int* __restrict__ nbr_r,
                                               int* __restrict__ nbr_c,
                                               int E, int N) {
    int part = blockIdx.x & (NPART - 1);
    int blk = blockIdx.x >> 4;
    int rpp = (N + NPART - 1) / NPART;
    int lo = part * rpp;
    int hi = lo + rpp;
    if (hi > N) hi = N;
    const int* key = blockIdx.y ? col : row;
    const int* val = blockIdx.y ? row : col;
    const int* ptr = blockIdx.y ? cptr : rptr;
    int* f = blockIdx.y ? fc : fr;
    int* nbr = blockIdx.y ? nbr_c : nbr_r;
    for (int e = blk * 256 + threadIdx.x; e < E; e += BLKS_PER_PART * 256) {
        int k = key[e];
        if (k >= lo && k < hi) {
            int p = ptr[k] + atomicAdd(&f[k], 1);
            nbr[p] = val[e];
        }
    }
}

// ---------------- fp8 gather: index-only adjacency + inv-table weights ----------------
__global__ __launch_bounds__(256) void k_gather_f8(const unsigned char* __restrict__ h8,
                                                   const int* __restrict__ rptr,
                                                   const int* __restrict__ nbr_r,
                                                   const int* __restrict__ cptr,
                                                   const int* __restrict__ nbr_c,
                                                   const float* __restrict__ inv_out,
                                                   const float* __restrict__ inv_in,
                                                   ushort* __restrict__ agg,
                                                   ushort* __restrict__ aggt, int N) {
    int wv = threadIdx.x >> 6, lane = threadIdx.x & 63;
    int half = lane >> 5, l32 = lane & 31;
    int n = blockIdx.x * 4 + wv;
    if (n >= N) return;
    const int* ptr;
    const int* nbr;
    const float* invt;
    float fac;
    ushort* out;
    if (blockIdx.y == 0) { ptr = rptr; nbr = nbr_r; invt = inv_in; fac = inv_out[n]; out = agg; }
    else                 { ptr = cptr; nbr = nbr_c; invt = inv_out; fac = inv_in[n]; out = aggt; }
    int s = ptr[n], t = ptr[n + 1];
    float a[8] = {};
    for (int base = s; base < t; base += 64) {
        int cnt = t - base;
        if (cnt > 64) cnt = 64;
        int idx = 0;
        float ww = 0.f;
        if (lane < cnt) {
            idx = nbr[base + lane];
            ww = invt[idx];
        }
        for (int i = 0; i < cnt; i += 8) {
            int n0 = i + half, n1 = i + 2 + half, n2 = i + 4 + half, n3 = i + 6 + half;
            int c0 = __shfl(idx, n0, 64); float w0 = __shfl(ww, n0, 64);
            int c1 = __shfl(idx, n1, 64); float w1 = __shfl(ww, n1, 64);
            int c2 = __shfl(idx, n2, 64); float w2 = __shfl(ww, n2, 64);
            int c3 = __shfl(idx, n3, 64); float w3 = __shfl(ww, n3, 64);
            uint2 v0 = ((const uint2*)(h8 + (size_t)c0 * FDIM))[l32];
            uint2 v1 = ((const uint2*)(h8 + (size_t)c1 * FDIM))[l32];
            uint2 v2 = ((const uint2*)(h8 + (size_t)c2 * FDIM))[l32];
            uint2 v3 = ((const uint2*)(h8 + (size_t)c3 * FDIM))[l32];
            ACC8(v0, w0);
            ACC8(v1, w1);
            ACC8(v2, w2);
            ACC8(v3, w3);
        }
    }
#pragma unroll
    for (int j = 0; j < 8; ++j) a[j] += __shfl_xor(a[j], 32, 64);
    if (half == 0) {
        u16x8 o;
#pragma unroll
        for (int j = 0; j < 8; ++j) o[j] = f2bf(a[j] * fac);
        ((u16x8*)(out + (size_t)n * FDIM))[l32] = o;
    }
}

// ---------------- MFMA dual GEMM layers 1-2: BM=64 x BN=128, dual-format epilogue ----------------
__global__ __launch_bounds__(256) void k_gemm12(const ushort* __restrict__ Ab,
                                                const ushort* __restrict__ Atb,
                                                const ushort* __restrict__ Wsb,
                                                const ushort* __restrict__ Wdb,
                                                const float* __restrict__ bs,
                                                const float* __restrict__ bd,
                                                ushort* __restrict__ outH,
                                                unsigned char* __restrict__ out8) {
    __shared__ char smA[8192];
    __shared__ char smAt[8192];
    __shared__ char smWs[16384];
    __shared__ char smWd[16384];

    const int tid = threadIdx.x;
    const int wv = tid >> 6, lane = tid & 63;
    const int n0 = blockIdx.x * 64;
    const int j0 = blockIdx.y * 128;

    const char* Abase = (const char*)Ab;
    const char* Atbase = (const char*)Atb;
    const char* Wsbase = (const char*)Wsb;
    const char* Wdbase = (const char*)Wdb;

    f32x4 accS[8] = {};
    f32x4 accD[8] = {};

    for (int k0 = 0; k0 < FDIM; k0 += 64) {
#pragma unroll
        for (int it = 0; it < 2; ++it) {
            int si = it * 256 + tid;
            int r = si >> 3, sl = si & 7;
            int gs = sl ^ (r & 7);
            size_t goff = (size_t)(n0 + r) * (FDIM * 2) + k0 * 2 + gs * 16;
            gl_lds16(Abase + goff, smA + si * 16);
            gl_lds16(Atbase + goff, smAt + si * 16);
        }
#pragma unroll
        for (int it = 0; it < 4; ++it) {
            int si = it * 256 + tid;
            int r = si >> 3, sl = si & 7;
            int gs = sl ^ (r & 7);
            size_t goff = (size_t)(j0 + r) * (FDIM * 2) + k0 * 2 + gs * 16;
            gl_lds16(Wsbase + goff, smWs + si * 16);
            gl_lds16(Wdbase + goff, smWd + si * 16);
        }
        __syncthreads();
#pragma unroll
        for (int kh = 0; kh < 2; ++kh) {
            int rA = wv * 16 + (lane & 15);
            int sA = (kh * 4 + (lane >> 4)) ^ (rA & 7);
            bf16x8 aS = *(const bf16x8*)(smA + rA * 128 + sA * 16);
            bf16x8 aT = *(const bf16x8*)(smAt + rA * 128 + sA * 16);
#pragma unroll
            for (int ni = 0; ni < 8; ++ni) {
                int rB = ni * 16 + (lane & 15);
                int sB = (kh * 4 + (lane >> 4)) ^ (rB & 7);
                bf16x8 bSv = *(const bf16x8*)(smWs + rB * 128 + sB * 16);
                bf16x8 bDv = *(const bf16x8*)(smWd + rB * 128 + sB * 16);
                accS[ni] = __builtin_amdgcn_mfma_f32_16x16x32_bf16(aS, bSv, accS[ni], 0, 0, 0);
                accD[ni] = __builtin_amdgcn_mfma_f32_16x16x32_bf16(aT, bDv, accD[ni], 0, 0, 0);
            }
        }
        __syncthreads();
    }

#pragma unroll
    for (int ni = 0; ni < 8; ++ni) {
        int j = j0 + ni * 16 + (lane & 15);
        float bsv = bs[j], bdv = bd[j];
#pragma unroll
        for (int r = 0; r < 4; ++r) {
            int n = n0 + wv * 16 + (lane >> 4) * 4 + r;
            float v = 0.5f * (accS[ni][r] + bsv) + 0.5f * (accD[ni][r] + bdv);
            v = fmaxf(v, 0.0f);
            if (out8) out8[(size_t)n * FDIM + j] = f2fp8(v);
            else outH[(size_t)n * FDIM + j] = f2bf(v);
        }
    }
}

// ---------------- MFMA layer-3 GEMM: zs/zd as bf16 padded to 64 cols ----------------
__global__ __launch_bounds__(256) void k_gemm3(const ushort* __restrict__ Hb,
                                               const ushort* __restrict__ Wsb,
                                               const ushort* __restrict__ Wdb,
                                               ushort* __restrict__ zsb,
                                               ushort* __restrict__ zdb) {
    __shared__ char smA[16384];
    __shared__ char smWs[8192];
    __shared__ char smWd[8192];

    const int tid = threadIdx.x;
    const int wv = tid >> 6, lane = tid & 63;
    const int n0 = blockIdx.x * 128;

    const char* Abase = (const char*)Hb;
    const char* Wsbase = (const char*)Wsb;
    const char* Wdbase = (const char*)Wdb;

    f32x4 accS[2][4] = {};
    f32x4 accD[2][4] = {};

    for (int k0 = 0; k0 < FDIM; k0 += 64) {
#pragma unroll
        for (int it = 0; it < 4; ++it) {
            int si = (wv * 4 + it) * 64 + lane;
            int r = si >> 3, sl = si & 7;
            int gs = sl ^ (r & 7);
            size_t goff = (size_t)(n0 + r) * (FDIM * 2) + k0 * 2 + gs * 16;
            gl_lds16(Abase + goff, smA + si * 16);
        }
#pragma unroll
        for (int it = 0; it < 2; ++it) {
            int si = (wv * 2 + it) * 64 + lane;
            int r = si >> 3, sl = si & 7;
            int gs = sl ^ (r & 7);
            size_t goff = (size_t)r * (FDIM * 2) + k0 * 2 + gs * 16;
            gl_lds16(Wsbase + goff, smWs + si * 16);
            gl_lds16(Wdbase + goff, smWd + si * 16);
        }
        __syncthreads();
#pragma unroll
        for (int kh = 0; kh < 2; ++kh) {
            bf16x8 aS[2], bS[4], bD[4];
#pragma unroll
            for (int mi = 0; mi < 2; ++mi) {
                int r = wv * 32 + mi * 16 + (lane & 15);
                int off = r * 128 + (((kh * 4 + (lane >> 4)) ^ (r & 7)) * 16);
                aS[mi] = *(const bf16x8*)(smA + off);
            }
#pragma unroll
            for (int ni = 0; ni < 4; ++ni) {
                int r = ni * 16 + (lane & 15);
                int off = r * 128 + (((kh * 4 + (lane >> 4)) ^ (r & 7)) * 16);
                bS[ni] = *(const bf16x8*)(smWs + off);
                bD[ni] = *(const bf16x8*)(smWd + off);
            }
#pragma unroll
            for (int mi = 0; mi < 2; ++mi)
#pragma unroll
                for (int ni = 0; ni < 4; ++ni) {
                    accS[mi][ni] = __builtin_amdgcn_mfma_f32_16x16x32_bf16(aS[mi], bS[ni], accS[mi][ni], 0, 0, 0);
                    accD[mi][ni] = __builtin_amdgcn_mfma_f32_16x16x32_bf16(aS[mi], bD[ni], accD[mi][ni], 0, 0, 0);
                }
        }
        __syncthreads();
    }

#pragma unroll
    for (int mi = 0; mi < 2; ++mi)
#pragma unroll
        for (int ni = 0; ni < 4; ++ni) {
            int j = ni * 16 + (lane & 15);
            f32x4 cs = accS[mi][ni], cd = accD[mi][ni];
#pragma unroll
            for (int r = 0; r < 4; ++r) {
                int n = n0 + wv * 32 + mi * 16 + (lane >> 4) * 4 + r;
                zsb[(size_t)n * ZPAD + j] = f2bf(cs[r]);
                zdb[(size_t)n * ZPAD + j] = f2bf(cd[r]);
            }
        }
}

// ---------------- layer 3: gather over padded-64 bf16 z + inv-table weights + log_softmax ----------------
__global__ __launch_bounds__(256) void k_l3(const ushort* __restrict__ zsb,
                                            const ushort* __restrict__ zdb,
                                            const int* __restrict__ rptr,
                                            const int* __restrict__ nbr_r,
                                            const int* __restrict__ cptr,
                                            const int* __restrict__ nbr_c,
                                            const float* __restrict__ inv_out,
                                            const float* __restrict__ inv_in,
                                            const float* __restrict__ bs,
                                            const float* __restrict__ bd,
                                            float* __restrict__ out, int N) {
    int wv = threadIdx.x >> 6, lane = threadIdx.x & 63;
    int grp = lane >> 4, sl = lane & 15;
    int n = blockIdx.x * 4 + wv;
    if (n >= N) return;
    float acc[2][4] = {};

#pragma unroll
    for (int dir = 0; dir < 2; ++dir) {
        const int* ptr = dir == 0 ? rptr : cptr;
        const int* nbr = dir == 0 ? nbr_r : nbr_c;
        const float* invt = dir == 0 ? inv_in : inv_out;
        const ushort* zb = dir == 0 ? zsb : zdb;
        int s = ptr[n], t = ptr[n + 1];
        for (int base = s; base < t; base += 64) {
            int cnt = t - base;
            if (cnt > 64) cnt = 64;
            int idx = 0;
            float ww = 0.f;
            if (lane < cnt) {
                idx = nbr[base + lane];
                ww = invt[idx];
            }
            for (int i = 0; i < cnt; i += 8) {
                int n0 = i + grp, n1 = i + 4 + grp;
                int c0 = __shfl(idx, n0, 64); float w0 = __shfl(ww, n0, 64);
                int c1 = __shfl(idx, n1, 64); float w1 = __shfl(ww, n1, 64);
                u16x4 v0 = ((const u16x4*)(zb + (size_t)c0 * ZPAD))[sl];
                u16x4 v1 = ((const u16x4*)(zb + (size_t)c1 * ZPAD))[sl];
#pragma unroll
                for (int j = 0; j < 4; ++j)
                    acc[dir][j] += w0 * b2f(v0[j]) + w1 * b2f(v1[j]);
            }
        }
    }

    float fac0 = 0.5f * inv_out[n], fac1 = 0.5f * inv_in[n];
    float a[4];
#pragma unroll
    for (int j = 0; j < 4; ++j) {
        a[j] = fac0 * acc[0][j] + fac1 * acc[1][j];
        a[j] += __shfl_xor(a[j], 16, 64);
        a[j] += __shfl_xor(a[j], 32, 64);
    }
    float val[4];
#pragma unroll
    for (int j = 0; j < 4; ++j) {
        int c = 4 * sl + j;
        val[j] = (c < CDIM) ? a[j] + 0.5f * (bs[c] + bd[c]) : -INFINITY;
    }
    float m = fmaxf(fmaxf(val[0], val[1]), fmaxf(val[2], val[3]));
    for (int off = 1; off < 16; off <<= 1) m = fmaxf(m, __shfl_xor(m, off, 64));
    float ex = 0.f;
#pragma unroll
    for (int j = 0; j < 4; ++j) ex += (4 * sl + j < CDIM) ? expf(val[j] - m) : 0.f;
    for (int off = 1; off < 16; off <<= 1) ex += __shfl_xor(ex, off, 64);
    float lse = logf(ex);
    if (grp == 0 && sl < 10) {
        float4 o;
        o.x = val[0] - m - lse;
        o.y = val[1] - m - lse;
        o.z = val[2] - m - lse;
        o.w = val[3] - m - lse;
        ((float4*)(out + (size_t)n * CDIM))[sl] = o;
    }
}

extern "C" void kernel_launch(void* const* d_in, const int* in_sizes, int n_in,
                              void* d_out, int out_size, void* d_ws, size_t ws_size,
                              hipStream_t stream) {
    const int N = in_sizes[0] / FDIM;
    const int E = in_sizes[1] / 2;
    const int NP = cdiv(N, NPAD_TO) * NPAD_TO;

    const float* x = (const float*)d_in[0];
    const int* ei = (const int*)d_in[1];
    const int* row = ei;
    const int* col = ei + E;
    const float* ws1 = (const float*)d_in[2];
    const float* bs1 = (const float*)d_in[3];
    const float* wd1 = (const float*)d_in[4];
    const float* bd1 = (const float*)d_in[5];
    const float* ws2 = (const float*)d_in[6];
    const float* bs2 = (const float*)d_in[7];
    const float* wd2 = (const float*)d_in[8];
    const float* bd2 = (const float*)d_in[9];
    const float* ws3 = (const float*)d_in[10];
    const float* bs3 = (const float*)d_in[11];
    const float* wd3 = (const float*)d_in[12];
    const float* bd3 = (const float*)d_in[13];
    float* out = (float*)d_out;

    // ---- workspace carve ----
    char* base = (char*)d_ws;
    int* cnt_r = (int*)base;        base += sizeof(int) * N;
    int* cnt_c = (int*)base;        base += sizeof(int) * N;
    int* fr = (int*)base;           base += sizeof(int) * N;
    int* fc = (int*)base;           base += sizeof(int) * N;
    int* rptr = (int*)base;         base += sizeof(int) * (N + 1);
    int* cptr = (int*)base;         base += sizeof(int) * (N + 1);
    int* bsum = (int*)base;         base += sizeof(int) * 512;
    float* inv_out = (float*)base;  base += sizeof(float) * N;
    float* inv_in = (float*)base;   base += sizeof(float) * N;
    base = (char*)(((size_t)base + 15) & ~(size_t)15);
    int* nbr_r = (int*)base;        base += sizeof(int) * E;
    int* nbr_c = (int*)base;        base += sizeof(int) * E;
    base = (char*)(((size_t)base + 255) & ~(size_t)255);
    unsigned char* xb8 = (unsigned char*)base;  base += (size_t)NP * FDIM;
    base = (char*)(((size_t)base + 255) & ~(size_t)255);
    unsigned char* hb8 = (unsigned char*)base;  base += (size_t)NP * FDIM;
    base = (char*)(((size_t)base + 255) & ~(size_t)255);
    ushort* hb = (ushort*)base;     base += sizeof(ushort) * (size_t)NP * FDIM;
    ushort* aggb = (ushort*)base;   base += sizeof(ushort) * (size_t)NP * FDIM;
    ushort* aggtb = (ushort*)base;  base += sizeof(ushort) * (size_t)NP * FDIM;
    ushort* wbuf = (ushort*)base;   base += sizeof(ushort) * (4 * 65536 + 2 * 16384);
    ushort* zsb = aggb;
    ushort* zdb = aggtb;

    ushort* w1s = wbuf;
    ushort* w1d = wbuf + 65536;
    ushort* w2s = wbuf + 2 * 65536;
    ushort* w2d = wbuf + 3 * 65536;
    ushort* w3s = wbuf + 4 * 65536;
    ushort* w3d = wbuf + 4 * 65536 + 16384;

    const int nb = cdiv(N, 256);
    const int n4 = N * FDIM / 4;
    const int wn = 4 * 65536 + 2 * 16384;

    // ---- prologue: zero counters, count + casts ----
    hipMemsetAsync(cnt_r, 0, sizeof(int) * 4 * (size_t)N, stream);  // cnt_r,cnt_c,fr,fc
    k_pro<<<cdiv(E + n4 + wn, 256), 256, 0, stream>>>(row, col, cnt_r, cnt_c, E,
                                                      x, n4, ws1, wd1, ws2, wd2, ws3, wd3,
                                                      xb8, wbuf);
    k_scan1<<<dim3(nb, 2), 256, 0, stream>>>(cnt_r, cnt_c, rptr, cptr, bsum, N);
    k_scan2<<<2, 256, 0, stream>>>(bsum, nb);
    k_scan3<<<dim3(nb, 2), 256, 0, stream>>>(rptr, cptr, bsum, cnt_r, cnt_c, inv_out, inv_in, N, E);
    k_fillp<<<dim3(NPART * BLKS_PER_PART, 2), 256, 0, stream>>>(row, col, rptr, cptr,
                                                                fr, fc, nbr_r, nbr_c, E, N);

    dim3 ggrid(cdiv(N, 4), 2);
    dim3 ggemm(NP / 64, 2);
    dim3 ggemm3(NP / 128, 1);

    // layer 1: gather(fp8 x) -> bf16 agg -> GEMM -> fp8 h
    k_gather_f8<<<ggrid, 256, 0, stream>>>(xb8, rptr, nbr_r, cptr, nbr_c, inv_out, inv_in, aggb, aggtb, N);
    k_gemm12<<<ggemm, 256, 0, stream>>>(aggb, aggtb, w1s, w1d, bs1, bd1, nullptr, hb8);

    // layer 2: gather(fp8 h) -> bf16 agg -> GEMM -> bf16 h (for gemm3)
    k_gather_f8<<<ggrid, 256, 0, stream>>>(hb8, rptr, nbr_r, cptr, nbr_c, inv_out, inv_in, aggb, aggtb, N);
    k_gemm12<<<ggemm, 256, 0, stream>>>(aggb, aggtb, w2s, w2d, bs2, bd2, hb, nullptr);

    // layer 3
    k_gemm3<<<ggemm3, 256, 0, stream>>>(hb, w3s, w3d, zsb, zdb);
    k_l3<<<cdiv(N, 4), 256, 0, stream>>>(zsb, zdb, rptr, nbr_r, cptr, nbr_c, inv_out, inv_in,
                                         bs3, bd3, out, N);
}

// Round 15
// 389.630 us; speedup vs baseline: 1.0884x; 1.0086x over previous
//
#include <hip/hip_runtime.h>
#include <math.h>

#define FDIM 256
#define CDIM 40
#define ZPAD 64
#define NPAD_TO 128
#define NPART 16
#define BLKS_PER_PART 64
#define CNT_BLKS (NPART * BLKS_PER_PART * 2)   // 2048 count blocks (16 parts x 64 blks x 2 dirs)

typedef __attribute__((ext_vector_type(8))) __bf16 bf16x8;
typedef __attribute__((ext_vector_type(4))) float f32x4;
typedef __attribute__((ext_vector_type(8))) ushort u16x8;
typedef __attribute__((ext_vector_type(4))) ushort u16x4;

static inline int cdiv(int a, int b) { return (a + b - 1) / b; }

__device__ __forceinline__ float b2f(ushort u) { return __uint_as_float(((unsigned)u) << 16); }
__device__ __forceinline__ ushort f2bf(float f) {
    unsigned u = __float_as_uint(f);
    unsigned r = (u + 0x7FFFu + ((u >> 16) & 1u)) >> 16;
    return (ushort)r;
}
__device__ __forceinline__ unsigned char f2fp8(float f) {
    int p = __builtin_amdgcn_cvt_pk_fp8_f32(f, f, 0, false);
    return (unsigned char)(p & 0xff);
}

__device__ __forceinline__ void gl_lds16(const void* gsrc, void* ldst) {
    __builtin_amdgcn_global_load_lds((const __attribute__((address_space(1))) unsigned*)gsrc,
                                     (__attribute__((address_space(3))) unsigned*)ldst, 16, 0, 0);
}

#define ACC8(v, w)                                                      \
    {                                                                   \
        auto p0 = __builtin_amdgcn_cvt_pk_f32_fp8((v).x, false);        \
        auto p1 = __builtin_amdgcn_cvt_pk_f32_fp8((v).x, true);         \
        auto p2 = __builtin_amdgcn_cvt_pk_f32_fp8((v).y, false);        \
        auto p3 = __builtin_amdgcn_cvt_pk_f32_fp8((v).y, true);         \
        a[0] += (w) * p0[0]; a[1] += (w) * p0[1];                       \
        a[2] += (w) * p1[0]; a[3] += (w) * p1[1];                       \
        a[4] += (w) * p2[0]; a[5] += (w) * p2[1];                       \
        a[6] += (w) * p3[0]; a[7] += (w) * p3[1];                       \
    }

// ---------------- fused prologue: XCD-partitioned degree count + x cast(fp8) + weight cast(bf16) ----
__global__ __launch_bounds__(256) void k_pro2(const int* __restrict__ row,
                                              const int* __restrict__ col,
                                              int* __restrict__ cnt_r,
                                              int* __restrict__ cnt_c, int E, int N,
                                              const float* __restrict__ x, int n4,
                                              const float* __restrict__ s1, const float* __restrict__ d1,
                                              const float* __restrict__ s2, const float* __restrict__ d2,
                                              const float* __restrict__ s3, const float* __restrict__ d3,
                                              unsigned char* __restrict__ xb8,
                                              ushort* __restrict__ wb) {
    int bid = blockIdx.x;
    if (bid < CNT_BLKS) {
        // partitioned count: part fixed -> bid%8 fixed -> XCD-local counter lines
        int part = bid & (NPART - 1);
        int dir = (bid >> 4) & 1;
        int blk = bid >> 5;                       // 0..63
        int rpp = (N + NPART - 1) / NPART;
        int lo = part * rpp;
        int hi = lo + rpp;
        if (hi > N) hi = N;
        const int* key = dir ? col : row;
        int* cnt = dir ? cnt_c : cnt_r;
        for (int e = blk * 256 + threadIdx.x; e < E; e += BLKS_PER_PART * 256) {
            int k = key[e];
            if (k >= lo && k < hi) atomicAdd(&cnt[k], 1);
        }
        return;
    }
    int i = (bid - CNT_BLKS) * 256 + threadIdx.x;
    if (i < n4) {
        float4 v = ((const float4*)x)[i];
        uchar4 o;
        o.x = f2fp8(v.x); o.y = f2fp8(v.y); o.z = f2fp8(v.z); o.w = f2fp8(v.w);
        ((uchar4*)xb8)[i] = o;
        return;
    }
    int o = i - n4;
    const int BIG = 256 * 256;
    const int SM = 64 * 256;
    if (o >= 4 * BIG + 2 * SM) return;
    float v;
    if (o < BIG) v = s1[o];
    else if (o < 2 * BIG) v = d1[o - BIG];
    else if (o < 3 * BIG) v = s2[o - 2 * BIG];
    else if (o < 4 * BIG) v = d2[o - 3 * BIG];
    else {
        int oo = o - 4 * BIG;
        const float* src = (oo < SM) ? s3 : d3;
        oo = (oo < SM) ? oo : oo - SM;
        int r = oo >> 8;
        v = (r < CDIM) ? src[(r << 8) + (oo & 255)] : 0.0f;
    }
    wb[o] = f2bf(v);
}

// ---------------- fused r/c scan ----------------
__global__ __launch_bounds__(256) void k_scan1(const int* __restrict__ cnt_r,
                                               const int* __restrict__ cnt_c,
                                               int* __restrict__ rptr,
                                               int* __restrict__ cptr,
                                               int* __restrict__ bsum, int n) {
    const int* cnt = blockIdx.y ? cnt_c : cnt_r;
    int* ptr = blockIdx.y ? cptr : rptr;
    __shared__ int s[256];
    int t = threadIdx.x;
    int i = blockIdx.x * 256 + t;
    int v = (i < n) ? cnt[i] : 0;
    s[t] = v;
    __syncthreads();
    for (int off = 1; off < 256; off <<= 1) {
        int u = (t >= off) ? s[t - off] : 0;
        __syncthreads();
        s[t] += u;
        __syncthreads();
    }
    if (i < n) ptr[i] = s[t] - v;
    if (t == 255) bsum[blockIdx.y * 256 + blockIdx.x] = s[255];
}

__global__ __launch_bounds__(256) void k_scan2(int* __restrict__ bsum, int nb) {
    int* b = bsum + blockIdx.x * 256;
    __shared__ int s[256];
    int t = threadIdx.x;
    int v = (t < nb) ? b[t] : 0;
    s[t] = v;
    __syncthreads();
    for (int off = 1; off < 256; off <<= 1) {
        int u = (t >= off) ? s[t - off] : 0;
        __syncthreads();
        s[t] += u;
        __syncthreads();
    }
    if (t < nb) b[t] = s[t] - v;
}

// scan3 + inv tables
__global__ __launch_bounds__(256) void k_scan3(int* __restrict__ rptr,
                                               int* __restrict__ cptr,
                                               const int* __restrict__ bsum,
                                               const int* __restrict__ cnt_r,
                                               const int* __restrict__ cnt_c,
                                               float* __restrict__ inv_out,
                                               float* __restrict__ inv_in,
                                               int n, int total) {
    int i = blockIdx.x * 256 + threadIdx.x;
    if (blockIdx.y == 0) {
        if (i < n) {
            rptr[i] += bsum[blockIdx.x];
            int cv = cnt_r[i];
            inv_out[i] = cv > 0 ? rsqrtf((float)cv) : 0.0f;
        }
        if (blockIdx.x == 0 && threadIdx.x == 0) rptr[n] = total;
    } else {
        if (i < n) {
            cptr[i] += bsum[256 + blockIdx.x];
            int cv = cnt_c[i];
            inv_in[i] = cv > 0 ? rsqrtf((float)cv) : 0.0f;
        }
        if (blockIdx.x == 0 && threadIdx.x == 0) cptr[n] = total;
    }
}

// ---------------- XCD-partitioned fill ----------------
__global__ __launch_bounds__(256) void k_fillp(const int* __restrict__ row,
                                               const int* __restrict__ col,
                                               const int* __restrict__ rptr,
                                               const int* __restrict__ cptr,
                                               int* __restrict__ fr, int* __restrict__ fc,
                                               int* __restrict__ nbr_r,
                                               int* __restrict__ nbr_c,
                                               int E, int N) {
    int part = blockIdx.x & (NPART - 1);
    int blk = blockIdx.x >> 4;
    int rpp = (N + NPART - 1) / NPART;
    int lo = part * rpp;
    int hi = lo + rpp;
    if (hi > N) hi = N;
    const int* key = blockIdx.y ? col : row;
    const int* val = blockIdx.y ? row : col;
    const int* ptr = blockIdx.y ? cptr : rptr;
    int* f = blockIdx.y ? fc : fr;
    int* nbr = blockIdx.y ? nbr_c : nbr_r;
    for (int e = blk * 256 + threadIdx.x; e < E; e += BLKS_PER_PART * 256) {
        int k = key[e];
        if (k >= lo && k < hi) {
            int p = ptr[k] + atomicAdd(&f[k], 1);
            nbr[p] = val[e];
        }
    }
}

// ---------------- fp8 gather: index-only adjacency + inv-table weights ----------------
__global__ __launch_bounds__(256) void k_gather_f8(const unsigned char* __restrict__ h8,
                                                   const int* __restrict__ rptr,
                                                   const int* __restrict__ nbr_r,
                                                   const int* __restrict__ cptr,
                                                   const int* __restrict__ nbr_c,
                                                   const float* __restrict__ inv_out,
                                                   const float* __restrict__ inv_in,
                                                   ushort* __restrict__ agg,
                                                   ushort* __restrict__ aggt, int N) {
    int wv = threadIdx.x >> 6, lane = threadIdx.x & 63;
    int half = lane >> 5, l32 = lane & 31;
    int n = blockIdx.x * 4 + wv;
    if (n >= N) return;
    const int* ptr;
    const int* nbr;
    const float* invt;
    float fac;
    ushort* out;
    if (blockIdx.y == 0) { ptr = rptr; nbr = nbr_r; invt = inv_in; fac = inv_out[n]; out = agg; }
    else                 { ptr = cptr; nbr = nbr_c; invt = inv_out; fac = inv_in[n]; out = aggt; }
    int s = ptr[n], t = ptr[n + 1];
    float a[8] = {};
    for (int base = s; base < t; base += 64) {
        int cnt = t - base;
        if (cnt > 64) cnt = 64;
        int idx = 0;
        float ww = 0.f;
        if (lane < cnt) {
            idx = nbr[base + lane];
            ww = invt[idx];
        }
        for (int i = 0; i < cnt; i += 8) {
            int n0 = i + half, n1 = i + 2 + half, n2 = i + 4 + half, n3 = i + 6 + half;
            int c0 = __shfl(idx, n0, 64); float w0 = __shfl(ww, n0, 64);
            int c1 = __shfl(idx, n1, 64); float w1 = __shfl(ww, n1, 64);
            int c2 = __shfl(idx, n2, 64); float w2 = __shfl(ww, n2, 64);
            int c3 = __shfl(idx, n3, 64); float w3 = __shfl(ww, n3, 64);
            uint2 v0 = ((const uint2*)(h8 + (size_t)c0 * FDIM))[l32];
            uint2 v1 = ((const uint2*)(h8 + (size_t)c1 * FDIM))[l32];
            uint2 v2 = ((const uint2*)(h8 + (size_t)c2 * FDIM))[l32];
            uint2 v3 = ((const uint2*)(h8 + (size_t)c3 * FDIM))[l32];
            ACC8(v0, w0);
            ACC8(v1, w1);
            ACC8(v2, w2);
            ACC8(v3, w3);
        }
    }
#pragma unroll
    for (int j = 0; j < 8; ++j) a[j] += __shfl_xor(a[j], 32, 64);
    if (half == 0) {
        u16x8 o;
#pragma unroll
        for (int j = 0; j < 8; ++j) o[j] = f2bf(a[j] * fac);
        ((u16x8*)(out + (size_t)n * FDIM))[l32] = o;
    }
}

// ---------------- MFMA dual GEMM layers 1-2: BM=64 x BN=128, dual-format epilogue ----------------
__global__ __launch_bounds__(256) void k_gemm12(const ushort* __restrict__ Ab,
                                                const ushort* __restrict__ Atb,
                                                const ushort* __restrict__ Wsb,
                                                const ushort* __restrict__ Wdb,
                                                const float* __restrict__ bs,
                                                const float* __restrict__ bd,
                                                ushort* __restrict__ outH,
                                                unsigned char* __restrict__ out8) {
    __shared__ char smA[8192];
    __shared__ char smAt[8192];
    __shared__ char smWs[16384];
    __shared__ char smWd[16384];

    const int tid = threadIdx.x;
    const int wv = tid >> 6, lane = tid & 63;
    const int n0 = blockIdx.x * 64;
    const int j0 = blockIdx.y * 128;

    const char* Abase = (const char*)Ab;
    const char* Atbase = (const char*)Atb;
    const char* Wsbase = (const char*)Wsb;
    const char* Wdbase = (const char*)Wdb;

    f32x4 accS[8] = {};
    f32x4 accD[8] = {};

    for (int k0 = 0; k0 < FDIM; k0 += 64) {
#pragma unroll
        for (int it = 0; it < 2; ++it) {
            int si = it * 256 + tid;
            int r = si >> 3, sl = si & 7;
            int gs = sl ^ (r & 7);
            size_t goff = (size_t)(n0 + r) * (FDIM * 2) + k0 * 2 + gs * 16;
            gl_lds16(Abase + goff, smA + si * 16);
            gl_lds16(Atbase + goff, smAt + si * 16);
        }
#pragma unroll
        for (int it = 0; it < 4; ++it) {
            int si = it * 256 + tid;
            int r = si >> 3, sl = si & 7;
            int gs = sl ^ (r & 7);
            size_t goff = (size_t)(j0 + r) * (FDIM * 2) + k0 * 2 + gs * 16;
            gl_lds16(Wsbase + goff, smWs + si * 16);
            gl_lds16(Wdbase + goff, smWd + si * 16);
        }
        __syncthreads();
#pragma unroll
        for (int kh = 0; kh < 2; ++kh) {
            int rA = wv * 16 + (lane & 15);
            int sA = (kh * 4 + (lane >> 4)) ^ (rA & 7);
            bf16x8 aS = *(const bf16x8*)(smA + rA * 128 + sA * 16);
            bf16x8 aT = *(const bf16x8*)(smAt + rA * 128 + sA * 16);
#pragma unroll
            for (int ni = 0; ni < 8; ++ni) {
                int rB = ni * 16 + (lane & 15);
                int sB = (kh * 4 + (lane >> 4)) ^ (rB & 7);
                bf16x8 bSv = *(const bf16x8*)(smWs + rB * 128 + sB * 16);
                bf16x8 bDv = *(const bf16x8*)(smWd + rB * 128 + sB * 16);
                accS[ni] = __builtin_amdgcn_mfma_f32_16x16x32_bf16(aS, bSv, accS[ni], 0, 0, 0);
                accD[ni] = __builtin_amdgcn_mfma_f32_16x16x32_bf16(aT, bDv, accD[ni], 0, 0, 0);
            }
        }
        __syncthreads();
    }

#pragma unroll
    for (int ni = 0; ni < 8; ++ni) {
        int j = j0 + ni * 16 + (lane & 15);
        float bsv = bs[j], bdv = bd[j];
#pragma unroll
        for (int r = 0; r < 4; ++r) {
            int n = n0 + wv * 16 + (lane >> 4) * 4 + r;
            float v = 0.5f * (accS[ni][r] + bsv) + 0.5f * (accD[ni][r] + bdv);
            v = fmaxf(v, 0.0f);
            if (out8) out8[(size_t)n * FDIM + j] = f2fp8(v);
            else outH[(size_t)n * FDIM + j] = f2bf(v);
        }
    }
}

// ---------------- MFMA layer-3 GEMM: zs/zd as fp8 padded to 64 cols ----------------
__global__ __launch_bounds__(256) void k_gemm3(const ushort* __restrict__ Hb,
                                               const ushort* __restrict__ Wsb,
                                               const ushort* __restrict__ Wdb,
                                               unsigned char* __restrict__ zs8,
                                               unsigned char* __restrict__ zd8) {
    __shared__ char smA[16384];
    __shared__ char smWs[8192];
    __shared__ char smWd[8192];

    const int tid = threadIdx.x;
    const int wv = tid >> 6, lane = tid & 63;
    const int n0 = blockIdx.x * 128;

    const char* Abase = (const char*)Hb;
    const char* Wsbase = (const char*)Wsb;
    const char* Wdbase = (const char*)Wdb;

    f32x4 accS[2][4] = {};
    f32x4 accD[2][4] = {};

    for (int k0 = 0; k0 < FDIM; k0 += 64) {
#pragma unroll
        for (int it = 0; it < 4; ++it) {
            int si = (wv * 4 + it) * 64 + lane;
            int r = si >> 3, sl = si & 7;
            int gs = sl ^ (r & 7);
            size_t goff = (size_t)(n0 + r) * (FDIM * 2) + k0 * 2 + gs * 16;
            gl_lds16(Abase + goff, smA + si * 16);
        }
#pragma unroll
        for (int it = 0; it < 2; ++it) {
            int si = (wv * 2 + it) * 64 + lane;
            int r = si >> 3, sl = si & 7;
            int gs = sl ^ (r & 7);
            size_t goff = (size_t)r * (FDIM * 2) + k0 * 2 + gs * 16;
            gl_lds16(Wsbase + goff, smWs + si * 16);
            gl_lds16(Wdbase + goff, smWd + si * 16);
        }
        __syncthreads();
#pragma unroll
        for (int kh = 0; kh < 2; ++kh) {
            bf16x8 aS[2], bS[4], bD[4];
#pragma unroll
            for (int mi = 0; mi < 2; ++mi) {
                int r = wv * 32 + mi * 16 + (lane & 15);
                int off = r * 128 + (((kh * 4 + (lane >> 4)) ^ (r & 7)) * 16);
                aS[mi] = *(const bf16x8*)(smA + off);
            }
#pragma unroll
            for (int ni = 0; ni < 4; ++ni) {
                int r = ni * 16 + (lane & 15);
                int off = r * 128 + (((kh * 4 + (lane >> 4)) ^ (r & 7)) * 16);
                bS[ni] = *(const bf16x8*)(smWs + off);
                bD[ni] = *(const bf16x8*)(smWd + off);
            }
#pragma unroll
            for (int mi = 0; mi < 2; ++mi)
#pragma unroll
                for (int ni = 0; ni < 4; ++ni) {
                    accS[mi][ni] = __builtin_amdgcn_mfma_f32_16x16x32_bf16(aS[mi], bS[ni], accS[mi][ni], 0, 0, 0);
                    accD[mi][ni] = __builtin_amdgcn_mfma_f32_16x16x32_bf16(aS[mi], bD[ni], accD[mi][ni], 0, 0, 0);
                }
        }
        __syncthreads();
    }

#pragma unroll
    for (int mi = 0; mi < 2; ++mi)
#pragma unroll
        for (int ni = 0; ni < 4; ++ni) {
            int j = ni * 16 + (lane & 15);
            f32x4 cs = accS[mi][ni], cd = accD[mi][ni];
#pragma unroll
            for (int r = 0; r < 4; ++r) {
                int n = n0 + wv * 32 + mi * 16 + (lane >> 4) * 4 + r;
                zs8[(size_t)n * ZPAD + j] = f2fp8(cs[r]);
                zd8[(size_t)n * ZPAD + j] = f2fp8(cd[r]);
            }
        }
}

// ---------------- layer 3: gather over fp8 z + inv-table weights + log_softmax ----------------
__global__ __launch_bounds__(256) void k_l3(const unsigned char* __restrict__ zs8,
                                            const unsigned char* __restrict__ zd8,
                                            const int* __restrict__ rptr,
                                            const int* __restrict__ nbr_r,
                                            const int* __restrict__ cptr,
                                            const int* __restrict__ nbr_c,
                                            const float* __restrict__ inv_out,
                                            const float* __restrict__ inv_in,
                                            const float* __restrict__ bs,
                                            const float* __restrict__ bd,
                                            float* __restrict__ out, int N) {
    int wv = threadIdx.x >> 6, lane = threadIdx.x & 63;
    int grp = lane >> 4, sl = lane & 15;
    int n = blockIdx.x * 4 + wv;
    if (n >= N) return;
    float acc[2][4] = {};

#pragma unroll
    for (int dir = 0; dir < 2; ++dir) {
        const int* ptr = dir == 0 ? rptr : cptr;
        const int* nbr = dir == 0 ? nbr_r : nbr_c;
        const float* invt = dir == 0 ? inv_in : inv_out;
        const unsigned char* zb = dir == 0 ? zs8 : zd8;
        int s = ptr[n], t = ptr[n + 1];
        for (int base = s; base < t; base += 64) {
            int cnt = t - base;
            if (cnt > 64) cnt = 64;
            int idx = 0;
            float ww = 0.f;
            if (lane < cnt) {
                idx = nbr[base + lane];
                ww = invt[idx];
            }
            for (int i = 0; i < cnt; i += 8) {
                int n0 = i + grp, n1 = i + 4 + grp;
                int c0 = __shfl(idx, n0, 64); float w0 = __shfl(ww, n0, 64);
                int c1 = __shfl(idx, n1, 64); float w1 = __shfl(ww, n1, 64);
                unsigned v0 = ((const unsigned*)(zb + (size_t)c0 * ZPAD))[sl];
                unsigned v1 = ((const unsigned*)(zb + (size_t)c1 * ZPAD))[sl];
                auto p00 = __builtin_amdgcn_cvt_pk_f32_fp8(v0, false);
                auto p01 = __builtin_amdgcn_cvt_pk_f32_fp8(v0, true);
                auto p10 = __builtin_amdgcn_cvt_pk_f32_fp8(v1, false);
                auto p11 = __builtin_amdgcn_cvt_pk_f32_fp8(v1, true);
                acc[dir][0] += w0 * p00[0] + w1 * p10[0];
                acc[dir][1] += w0 * p00[1] + w1 * p10[1];
                acc[dir][2] += w0 * p01[0] + w1 * p11[0];
                acc[dir][3] += w0 * p01[1] + w1 * p11[1];
            }
        }
    }

    float fac0 = 0.5f * inv_out[n], fac1 = 0.5f * inv_in[n];
    float a[4];
#pragma unroll
    for (int j = 0; j < 4; ++j) {
        a[j] = fac0 * acc[0][j] + fac1 * acc[1][j];
        a[j] += __shfl_xor(a[j], 16, 64);
        a[j] += __shfl_xor(a[j], 32, 64);
    }
    float val[4];
#pragma unroll
    for (int j = 0; j < 4; ++j) {
        int c = 4 * sl + j;
        val[j] = (c < CDIM) ? a[j] + 0.5f * (bs[c] + bd[c]) : -INFINITY;
    }
    float m = fmaxf(fmaxf(val[0], val[1]), fmaxf(val[2], val[3]));
    for (int off = 1; off < 16; off <<= 1) m = fmaxf(m, __shfl_xor(m, off, 64));
    float ex = 0.f;
#pragma unroll
    for (int j = 0; j < 4; ++j) ex += (4 * sl + j < CDIM) ? expf(val[j] - m) : 0.f;
    for (int off = 1; off < 16; off <<= 1) ex += __shfl_xor(ex, off, 64);
    float lse = logf(ex);
    if (grp == 0 && sl < 10) {
        float4 o;
        o.x = val[0] - m - lse;
        o.y = val[1] - m - lse;
        o.z = val[2] - m - lse;
        o.w = val[3] - m - lse;
        ((float4*)(out + (size_t)n * CDIM))[sl] = o;
    }
}

extern "C" void kernel_launch(void* const* d_in, const int* in_sizes, int n_in,
                              void* d_out, int out_size, void* d_ws, size_t ws_size,
                              hipStream_t stream) {
    const int N = in_sizes[0] / FDIM;
    const int E = in_sizes[1] / 2;
    const int NP = cdiv(N, NPAD_TO) * NPAD_TO;

    const float* x = (const float*)d_in[0];
    const int* ei = (const int*)d_in[1];
    const int* row = ei;
    const int* col = ei + E;
    const float* ws1 = (const float*)d_in[2];
    const float* bs1 = (const float*)d_in[3];
    const float* wd1 = (const float*)d_in[4];
    const float* bd1 = (const float*)d_in[5];
    const float* ws2 = (const float*)d_in[6];
    const float* bs2 = (const float*)d_in[7];
    const float* wd2 = (const float*)d_in[8];
    const float* bd2 = (const float*)d_in[9];
    const float* ws3 = (const float*)d_in[10];
    const float* bs3 = (const float*)d_in[11];
    const float* wd3 = (const float*)d_in[12];
    const float* bd3 = (const float*)d_in[13];
    float* out = (float*)d_out;

    // ---- workspace carve ----
    char* base = (char*)d_ws;
    int* cnt_r = (int*)base;        base += sizeof(int) * N;
    int* cnt_c = (int*)base;        base += sizeof(int) * N;
    int* fr = (int*)base;           base += sizeof(int) * N;
    int* fc = (int*)base;           base += sizeof(int) * N;
    int* rptr = (int*)base;         base += sizeof(int) * (N + 1);
    int* cptr = (int*)base;         base += sizeof(int) * (N + 1);
    int* bsum = (int*)base;         base += sizeof(int) * 512;
    float* inv_out = (float*)base;  base += sizeof(float) * N;
    float* inv_in = (float*)base;   base += sizeof(float) * N;
    base = (char*)(((size_t)base + 15) & ~(size_t)15);
    int* nbr_r = (int*)base;        base += sizeof(int) * E;
    int* nbr_c = (int*)base;        base += sizeof(int) * E;
    base = (char*)(((size_t)base + 255) & ~(size_t)255);
    unsigned char* xb8 = (unsigned char*)base;  base += (size_t)NP * FDIM;
    base = (char*)(((size_t)base + 255) & ~(size_t)255);
    unsigned char* hb8 = (unsigned char*)base;  base += (size_t)NP * FDIM;
    base = (char*)(((size_t)base + 255) & ~(size_t)255);
    ushort* hb = (ushort*)base;     base += sizeof(ushort) * (size_t)NP * FDIM;
    ushort* aggb = (ushort*)base;   base += sizeof(ushort) * (size_t)NP * FDIM;
    ushort* aggtb = (ushort*)base;  base += sizeof(ushort) * (size_t)NP * FDIM;
    ushort* wbuf = (ushort*)base;   base += sizeof(ushort) * (4 * 65536 + 2 * 16384);
    unsigned char* zs8 = (unsigned char*)aggb;   // z aliases agg buffers (fp8, 64B rows)
    unsigned char* zd8 = (unsigned char*)aggtb;

    ushort* w1s = wbuf;
    ushort* w1d = wbuf + 65536;
    ushort* w2s = wbuf + 2 * 65536;
    ushort* w2d = wbuf + 3 * 65536;
    ushort* w3s = wbuf + 4 * 65536;
    ushort* w3d = wbuf + 4 * 65536 + 16384;

    const int nb = cdiv(N, 256);
    const int n4 = N * FDIM / 4;
    const int wn = 4 * 65536 + 2 * 16384;

    // ---- prologue: zero counters, partitioned count + casts, scans, partitioned fill ----
    hipMemsetAsync(cnt_r, 0, sizeof(int) * 4 * (size_t)N, stream);  // cnt_r,cnt_c,fr,fc
    k_pro2<<<CNT_BLKS + cdiv(n4 + wn, 256), 256, 0, stream>>>(row, col, cnt_r, cnt_c, E, N,
                                                              x, n4, ws1, wd1, ws2, wd2, ws3, wd3,
                                                              xb8, wbuf);
    k_scan1<<<dim3(nb, 2), 256, 0, stream>>>(cnt_r, cnt_c, rptr, cptr, bsum, N);
    k_scan2<<<2, 256, 0, stream>>>(bsum, nb);
    k_scan3<<<dim3(nb, 2), 256, 0, stream>>>(rptr, cptr, bsum, cnt_r, cnt_c, inv_out, inv_in, N, E);
    k_fillp<<<dim3(NPART * BLKS_PER_PART, 2), 256, 0, stream>>>(row, col, rptr, cptr,
                                                                fr, fc, nbr_r, nbr_c, E, N);

    dim3 ggrid(cdiv(N, 4), 2);
    dim3 ggemm(NP / 64, 2);
    dim3 ggemm3(NP / 128, 1);

    // layer 1: gather(fp8 x) -> bf16 agg -> GEMM -> fp8 h
    k_gather_f8<<<ggrid, 256, 0, stream>>>(xb8, rptr, nbr_r, cptr, nbr_c, inv_out, inv_in, aggb, aggtb, N);
    k_gemm12<<<ggemm, 256, 0, stream>>>(aggb, aggtb, w1s, w1d, bs1, bd1, nullptr, hb8);

    // layer 2: gather(fp8 h) -> bf16 agg -> GEMM -> bf16 h (for gemm3)
    k_gather_f8<<<ggrid, 256, 0, stream>>>(hb8, rptr, nbr_r, cptr, nbr_c, inv_out, inv_in, aggb, aggtb, N);
    k_gemm12<<<ggemm, 256, 0, stream>>>(aggb, aggtb, w2s, w2d, bs2, bd2, hb, nullptr);

    // layer 3
    k_gemm3<<<ggemm3, 256, 0, stream>>>(hb, w3s, w3d, zs8, zd8);
    k_l3<<<cdiv(N, 4), 256, 0, stream>>>(zs8, zd8, rptr, nbr_r, cptr, nbr_c, inv_out, inv_in,
                                         bs3, bd3, out, N);
}

// Round 16
// 347.258 us; speedup vs baseline: 1.2212x; 1.1220x over previous
//
#include <hip/hip_runtime.h>
#include <math.h>

#define FDIM 256
#define CDIM 40
#define ZPAD 64
#define NPAD_TO 128
#define NPART 8
#define NBLK 32
#define CNTB (2 * NPART * NBLK)   // 512 build blocks
#define RSZMAX 6400               // LDS histogram capacity (N <= NPART*RSZMAX)

typedef __attribute__((ext_vector_type(8))) __bf16 bf16x8;
typedef __attribute__((ext_vector_type(4))) float f32x4;
typedef __attribute__((ext_vector_type(8))) ushort u16x8;
typedef __attribute__((ext_vector_type(4))) ushort u16x4;

static inline int cdiv(int a, int b) { return (a + b - 1) / b; }

__device__ __forceinline__ float b2f(ushort u) { return __uint_as_float(((unsigned)u) << 16); }
__device__ __forceinline__ ushort f2bf(float f) {
    unsigned u = __float_as_uint(f);
    unsigned r = (u + 0x7FFFu + ((u >> 16) & 1u)) >> 16;
    return (ushort)r;
}
__device__ __forceinline__ unsigned char f2fp8(float f) {
    int p = __builtin_amdgcn_cvt_pk_fp8_f32(f, f, 0, false);
    return (unsigned char)(p & 0xff);
}

__device__ __forceinline__ void gl_lds16(const void* gsrc, void* ldst) {
    __builtin_amdgcn_global_load_lds((const __attribute__((address_space(1))) unsigned*)gsrc,
                                     (__attribute__((address_space(3))) unsigned*)ldst, 16, 0, 0);
}

#define ACC8(v, w)                                                      \
    {                                                                   \
        auto p0 = __builtin_amdgcn_cvt_pk_f32_fp8((v).x, false);        \
        auto p1 = __builtin_amdgcn_cvt_pk_f32_fp8((v).x, true);         \
        auto p2 = __builtin_amdgcn_cvt_pk_f32_fp8((v).y, false);        \
        auto p3 = __builtin_amdgcn_cvt_pk_f32_fp8((v).y, true);         \
        a[0] += (w) * p0[0]; a[1] += (w) * p0[1];                       \
        a[2] += (w) * p1[0]; a[3] += (w) * p1[1];                       \
        a[4] += (w) * p2[0]; a[5] += (w) * p2[1];                       \
        a[6] += (w) * p3[0]; a[7] += (w) * p3[1];                       \
    }

// ---------------- pass 1: LDS-histogram count (no global atomics) + fused casts ----------------
__global__ __launch_bounds__(256) void k_cnt(const int* __restrict__ row,
                                             const int* __restrict__ col,
                                             int* __restrict__ blkcnt, int E, int N,
                                             const float* __restrict__ x, int n4,
                                             const float* __restrict__ s1, const float* __restrict__ d1,
                                             const float* __restrict__ s2, const float* __restrict__ d2,
                                             const float* __restrict__ s3, const float* __restrict__ d3,
                                             unsigned char* __restrict__ xb8,
                                             ushort* __restrict__ wb) {
    int bid = blockIdx.x;
    if (bid < CNTB) {
        int dir = bid >> 8;           // NPART*NBLK = 256
        int rest = bid & 255;
        int part = rest >> 5;
        int blk = rest & 31;
        int rpp = (N + NPART - 1) / NPART;
        int lo = part * rpp;
        int hi = lo + rpp;
        if (hi > N) hi = N;
        __shared__ unsigned hist[RSZMAX];
        for (int i = threadIdx.x; i < rpp; i += 256) hist[i] = 0;
        __syncthreads();
        const int* key = dir ? col : row;
        int per = (E + NBLK - 1) / NBLK;
        int e0 = blk * per;
        int e1 = e0 + per;
        if (e1 > E) e1 = E;
        for (int e = e0 + threadIdx.x; e < e1; e += 256) {
            int k = key[e];
            if (k >= lo && k < hi) atomicAdd(&hist[k - lo], 1u);
        }
        __syncthreads();
        int* dst = blkcnt + ((size_t)(dir * NPART + part) * NBLK + blk) * rpp;
        for (int i = threadIdx.x; i < rpp; i += 256) dst[i] = (int)hist[i];
        return;
    }
    int i = (bid - CNTB) * 256 + threadIdx.x;
    if (i < n4) {
        float4 v = ((const float4*)x)[i];
        uchar4 o;
        o.x = f2fp8(v.x); o.y = f2fp8(v.y); o.z = f2fp8(v.z); o.w = f2fp8(v.w);
        ((uchar4*)xb8)[i] = o;
        return;
    }
    int o = i - n4;
    const int BIG = 256 * 256;
    const int SM = 64 * 256;
    if (o >= 4 * BIG + 2 * SM) return;
    float v;
    if (o < BIG) v = s1[o];
    else if (o < 2 * BIG) v = d1[o - BIG];
    else if (o < 3 * BIG) v = s2[o - 2 * BIG];
    else if (o < 4 * BIG) v = d2[o - 3 * BIG];
    else {
        int oo = o - 4 * BIG;
        const float* src = (oo < SM) ? s3 : d3;
        oo = (oo < SM) ? oo : oo - SM;
        int r = oo >> 8;
        v = (r < CDIM) ? src[(r << 8) + (oo & 255)] : 0.0f;
    }
    wb[o] = f2bf(v);
}

// ---------------- reduce: per-node exclusive scan over 32 block counts (in place) + degree + inv ----
__global__ __launch_bounds__(256) void k_red(int* __restrict__ blkcnt,
                                             int* __restrict__ cnt_r,
                                             int* __restrict__ cnt_c,
                                             float* __restrict__ inv_out,
                                             float* __restrict__ inv_in, int N) {
    int dir = blockIdx.y;
    int n = blockIdx.x * 256 + threadIdx.x;
    if (n >= N) return;
    int rpp = (N + NPART - 1) / NPART;
    int part = n / rpp, i = n - part * rpp;
    int* p = blkcnt + ((size_t)(dir * NPART + part) * NBLK) * rpp + i;
    int s = 0;
#pragma unroll
    for (int b = 0; b < NBLK; ++b) {
        int v = p[(size_t)b * rpp];
        p[(size_t)b * rpp] = s;
        s += v;
    }
    float iv = s > 0 ? rsqrtf((float)s) : 0.0f;
    if (dir == 0) { cnt_r[n] = s; inv_out[n] = iv; }
    else          { cnt_c[n] = s; inv_in[n] = iv; }
}

// ---------------- fused r/c scan ----------------
__global__ __launch_bounds__(256) void k_scan1(const int* __restrict__ cnt_r,
                                               const int* __restrict__ cnt_c,
                                               int* __restrict__ rptr,
                                               int* __restrict__ cptr,
                                               int* __restrict__ bsum, int n) {
    const int* cnt = blockIdx.y ? cnt_c : cnt_r;
    int* ptr = blockIdx.y ? cptr : rptr;
    __shared__ int s[256];
    int t = threadIdx.x;
    int i = blockIdx.x * 256 + t;
    int v = (i < n) ? cnt[i] : 0;
    s[t] = v;
    __syncthreads();
    for (int off = 1; off < 256; off <<= 1) {
        int u = (t >= off) ? s[t - off] : 0;
        __syncthreads();
        s[t] += u;
        __syncthreads();
    }
    if (i < n) ptr[i] = s[t] - v;
    if (t == 255) bsum[blockIdx.y * 256 + blockIdx.x] = s[255];
}

__global__ __launch_bounds__(256) void k_scan2(int* __restrict__ bsum, int nb) {
    int* b = bsum + blockIdx.x * 256;
    __shared__ int s[256];
    int t = threadIdx.x;
    int v = (t < nb) ? b[t] : 0;
    s[t] = v;
    __syncthreads();
    for (int off = 1; off < 256; off <<= 1) {
        int u = (t >= off) ? s[t - off] : 0;
        __syncthreads();
        s[t] += u;
        __syncthreads();
    }
    if (t < nb) b[t] = s[t] - v;
}

__global__ __launch_bounds__(256) void k_scan3(int* __restrict__ rptr,
                                               int* __restrict__ cptr,
                                               const int* __restrict__ bsum,
                                               int n, int total) {
    int* ptr = blockIdx.y ? cptr : rptr;
    int i = blockIdx.x * 256 + threadIdx.x;
    if (i < n) ptr[i] += bsum[blockIdx.y * 256 + blockIdx.x];
    if (blockIdx.x == 0 && threadIdx.x == 0) ptr[n] = total;
}

// ---------------- pass 2: place entries via per-block offsets + LDS running counts ----------------
// part = bid&7 -> fixed bid%8 -> nbr stores XCD-local (R14-validated heuristic).
__global__ __launch_bounds__(256) void k_fill2(const int* __restrict__ row,
                                               const int* __restrict__ col,
                                               const int* __restrict__ rptr,
                                               const int* __restrict__ cptr,
                                               const int* __restrict__ blkoff,
                                               int* __restrict__ nbr_r,
                                               int* __restrict__ nbr_c,
                                               int E, int N) {
    int bid = blockIdx.x;              // 0..511
    int part = bid & 7;
    int rest = bid >> 3;               // 0..63
    int dir = rest >> 5;
    int blk = rest & 31;
    int rpp = (N + NPART - 1) / NPART;
    int lo = part * rpp;
    int hi = lo + rpp;
    if (hi > N) hi = N;
    __shared__ unsigned used[RSZMAX];
    for (int i = threadIdx.x; i < rpp; i += 256) used[i] = 0;
    __syncthreads();
    const int* key = dir ? col : row;
    const int* val = dir ? row : col;
    const int* ptr = dir ? cptr : rptr;
    int* nbr = dir ? nbr_c : nbr_r;
    const int* off = blkoff + ((size_t)(dir * NPART + part) * NBLK + blk) * rpp;
    int per = (E + NBLK - 1) / NBLK;
    int e0 = blk * per;
    int e1 = e0 + per;
    if (e1 > E) e1 = E;
    for (int e = e0 + threadIdx.x; e < e1; e += 256) {
        int k = key[e];
        if (k >= lo && k < hi) {
            int u = (int)atomicAdd(&used[k - lo], 1u);
            nbr[ptr[k] + off[k - lo] + u] = val[e];
        }
    }
}

// ---------------- fp8 gather: index-only adjacency + inv-table weights ----------------
__global__ __launch_bounds__(256) void k_gather_f8(const unsigned char* __restrict__ h8,
                                                   const int* __restrict__ rptr,
                                                   const int* __restrict__ nbr_r,
                                                   const int* __restrict__ cptr,
                                                   const int* __restrict__ nbr_c,
                                                   const float* __restrict__ inv_out,
                                                   const float* __restrict__ inv_in,
                                                   ushort* __restrict__ agg,
                                                   ushort* __restrict__ aggt, int N) {
    int wv = threadIdx.x >> 6, lane = threadIdx.x & 63;
    int half = lane >> 5, l32 = lane & 31;
    int n = blockIdx.x * 4 + wv;
    if (n >= N) return;
    const int* ptr;
    const int* nbr;
    const float* invt;
    float fac;
    ushort* out;
    if (blockIdx.y == 0) { ptr = rptr; nbr = nbr_r; invt = inv_in; fac = inv_out[n]; out = agg; }
    else                 { ptr = cptr; nbr = nbr_c; invt = inv_out; fac = inv_in[n]; out = aggt; }
    int s = ptr[n], t = ptr[n + 1];
    float a[8] = {};
    for (int base = s; base < t; base += 64) {
        int cnt = t - base;
        if (cnt > 64) cnt = 64;
        int idx = 0;
        float ww = 0.f;
        if (lane < cnt) {
            idx = nbr[base + lane];
            ww = invt[idx];
        }
        for (int i = 0; i < cnt; i += 8) {
            int n0 = i + half, n1 = i + 2 + half, n2 = i + 4 + half, n3 = i + 6 + half;
            int c0 = __shfl(idx, n0, 64); float w0 = __shfl(ww, n0, 64);
            int c1 = __shfl(idx, n1, 64); float w1 = __shfl(ww, n1, 64);
            int c2 = __shfl(idx, n2, 64); float w2 = __shfl(ww, n2, 64);
            int c3 = __shfl(idx, n3, 64); float w3 = __shfl(ww, n3, 64);
            uint2 v0 = ((const uint2*)(h8 + (size_t)c0 * FDIM))[l32];
            uint2 v1 = ((const uint2*)(h8 + (size_t)c1 * FDIM))[l32];
            uint2 v2 = ((const uint2*)(h8 + (size_t)c2 * FDIM))[l32];
            uint2 v3 = ((const uint2*)(h8 + (size_t)c3 * FDIM))[l32];
            ACC8(v0, w0);
            ACC8(v1, w1);
            ACC8(v2, w2);
            ACC8(v3, w3);
        }
    }
#pragma unroll
    for (int j = 0; j < 8; ++j) a[j] += __shfl_xor(a[j], 32, 64);
    if (half == 0) {
        u16x8 o;
#pragma unroll
        for (int j = 0; j < 8; ++j) o[j] = f2bf(a[j] * fac);
        ((u16x8*)(out + (size_t)n * FDIM))[l32] = o;
    }
}

// ---------------- MFMA dual GEMM layers 1-2: BM=64 x BN=128, dual-format epilogue ----------------
__global__ __launch_bounds__(256) void k_gemm12(const ushort* __restrict__ Ab,
                                                const ushort* __restrict__ Atb,
                                                const ushort* __restrict__ Wsb,
                                                const ushort* __restrict__ Wdb,
                                                const float* __restrict__ bs,
                                                const float* __restrict__ bd,
                                                ushort* __restrict__ outH,
                                                unsigned char* __restrict__ out8) {
    __shared__ char smA[8192];
    __shared__ char smAt[8192];
    __shared__ char smWs[16384];
    __shared__ char smWd[16384];

    const int tid = threadIdx.x;
    const int wv = tid >> 6, lane = tid & 63;
    const int n0 = blockIdx.x * 64;
    const int j0 = blockIdx.y * 128;

    const char* Abase = (const char*)Ab;
    const char* Atbase = (const char*)Atb;
    const char* Wsbase = (const char*)Wsb;
    const char* Wdbase = (const char*)Wdb;

    f32x4 accS[8] = {};
    f32x4 accD[8] = {};

    for (int k0 = 0; k0 < FDIM; k0 += 64) {
#pragma unroll
        for (int it = 0; it < 2; ++it) {
            int si = it * 256 + tid;
            int r = si >> 3, sl = si & 7;
            int gs = sl ^ (r & 7);
            size_t goff = (size_t)(n0 + r) * (FDIM * 2) + k0 * 2 + gs * 16;
            gl_lds16(Abase + goff, smA + si * 16);
            gl_lds16(Atbase + goff, smAt + si * 16);
        }
#pragma unroll
        for (int it = 0; it < 4; ++it) {
            int si = it * 256 + tid;
            int r = si >> 3, sl = si & 7;
            int gs = sl ^ (r & 7);
            size_t goff = (size_t)(j0 + r) * (FDIM * 2) + k0 * 2 + gs * 16;
            gl_lds16(Wsbase + goff, smWs + si * 16);
            gl_lds16(Wdbase + goff, smWd + si * 16);
        }
        __syncthreads();
#pragma unroll
        for (int kh = 0; kh < 2; ++kh) {
            int rA = wv * 16 + (lane & 15);
            int sA = (kh * 4 + (lane >> 4)) ^ (rA & 7);
            bf16x8 aS = *(const bf16x8*)(smA + rA * 128 + sA * 16);
            bf16x8 aT = *(const bf16x8*)(smAt + rA * 128 + sA * 16);
#pragma unroll
            for (int ni = 0; ni < 8; ++ni) {
                int rB = ni * 16 + (lane & 15);
                int sB = (kh * 4 + (lane >> 4)) ^ (rB & 7);
                bf16x8 bSv = *(const bf16x8*)(smWs + rB * 128 + sB * 16);
                bf16x8 bDv = *(const bf16x8*)(smWd + rB * 128 + sB * 16);
                accS[ni] = __builtin_amdgcn_mfma_f32_16x16x32_bf16(aS, bSv, accS[ni], 0, 0, 0);
                accD[ni] = __builtin_amdgcn_mfma_f32_16x16x32_bf16(aT, bDv, accD[ni], 0, 0, 0);
            }
        }
        __syncthreads();
    }

#pragma unroll
    for (int ni = 0; ni < 8; ++ni) {
        int j = j0 + ni * 16 + (lane & 15);
        float bsv = bs[j], bdv = bd[j];
#pragma unroll
        for (int r = 0; r < 4; ++r) {
            int n = n0 + wv * 16 + (lane >> 4) * 4 + r;
            float v = 0.5f * (accS[ni][r] + bsv) + 0.5f * (accD[ni][r] + bdv);
            v = fmaxf(v, 0.0f);
            if (out8) out8[(size_t)n * FDIM + j] = f2fp8(v);
            else outH[(size_t)n * FDIM + j] = f2bf(v);
        }
    }
}

// ---------------- MFMA layer-3 GEMM: zs/zd as fp8 padded to 64 cols ----------------
__global__ __launch_bounds__(256) void k_gemm3(const ushort* __restrict__ Hb,
                                               const ushort* __restrict__ Wsb,
                                               const ushort* __restrict__ Wdb,
                                               unsigned char* __restrict__ zs8,
                                               unsigned char* __restrict__ zd8) {
    __shared__ char smA[16384];
    __shared__ char smWs[8192];
    __shared__ char smWd[8192];

    const int tid = threadIdx.x;
    const int wv = tid >> 6, lane = tid & 63;
    const int n0 = blockIdx.x * 128;

    const char* Abase = (const char*)Hb;
    const char* Wsbase = (const char*)Wsb;
    const char* Wdbase = (const char*)Wdb;

    f32x4 accS[2][4] = {};
    f32x4 accD[2][4] = {};

    for (int k0 = 0; k0 < FDIM; k0 += 64) {
#pragma unroll
        for (int it = 0; it < 4; ++it) {
            int si = (wv * 4 + it) * 64 + lane;
            int r = si >> 3, sl = si & 7;
            int gs = sl ^ (r & 7);
            size_t goff = (size_t)(n0 + r) * (FDIM * 2) + k0 * 2 + gs * 16;
            gl_lds16(Abase + goff, smA + si * 16);
        }
#pragma unroll
        for (int it = 0; it < 2; ++it) {
            int si = (wv * 2 + it) * 64 + lane;
            int r = si >> 3, sl = si & 7;
            int gs = sl ^ (r & 7);
            size_t goff = (size_t)r * (FDIM * 2) + k0 * 2 + gs * 16;
            gl_lds16(Wsbase + goff, smWs + si * 16);
            gl_lds16(Wdbase + goff, smWd + si * 16);
        }
        __syncthreads();
#pragma unroll
        for (int kh = 0; kh < 2; ++kh) {
            bf16x8 aS[2], bS[4], bD[4];
#pragma unroll
            for (int mi = 0; mi < 2; ++mi) {
                int r = wv * 32 + mi * 16 + (lane & 15);
                int off = r * 128 + (((kh * 4 + (lane >> 4)) ^ (r & 7)) * 16);
                aS[mi] = *(const bf16x8*)(smA + off);
            }
#pragma unroll
            for (int ni = 0; ni < 4; ++ni) {
                int r = ni * 16 + (lane & 15);
                int off = r * 128 + (((kh * 4 + (lane >> 4)) ^ (r & 7)) * 16);
                bS[ni] = *(const bf16x8*)(smWs + off);
                bD[ni] = *(const bf16x8*)(smWd + off);
            }
#pragma unroll
            for (int mi = 0; mi < 2; ++mi)
#pragma unroll
                for (int ni = 0; ni < 4; ++ni) {
                    accS[mi][ni] = __builtin_amdgcn_mfma_f32_16x16x32_bf16(aS[mi], bS[ni], accS[mi][ni], 0, 0, 0);
                    accD[mi][ni] = __builtin_amdgcn_mfma_f32_16x16x32_bf16(aS[mi], bD[ni], accD[mi][ni], 0, 0, 0);
                }
        }
        __syncthreads();
    }

#pragma unroll
    for (int mi = 0; mi < 2; ++mi)
#pragma unroll
        for (int ni = 0; ni < 4; ++ni) {
            int j = ni * 16 + (lane & 15);
            f32x4 cs = accS[mi][ni], cd = accD[mi][ni];
#pragma unroll
            for (int r = 0; r < 4; ++r) {
                int n = n0 + wv * 32 + mi * 16 + (lane >> 4) * 4 + r;
                zs8[(size_t)n * ZPAD + j] = f2fp8(cs[r]);
                zd8[(size_t)n * ZPAD + j] = f2fp8(cd[r]);
            }
        }
}

// ---------------- layer 3: gather over fp8 z + inv-table weights + log_softmax ----------------
__global__ __launch_bounds__(256) void k_l3(const unsigned char* __restrict__ zs8,
                                            const unsigned char* __restrict__ zd8,
                                            const int* __restrict__ rptr,
                                            const int* __restrict__ nbr_r,
                                            const int* __restrict__ cptr,
                                            const int* __restrict__ nbr_c,
                                            const float* __restrict__ inv_out,
                                            const float* __restrict__ inv_in,
                                            const float* __restrict__ bs,
                                            const float* __restrict__ bd,
                                            float* __restrict__ out, int N) {
    int wv = threadIdx.x >> 6, lane = threadIdx.x & 63;
    int grp = lane >> 4, sl = lane & 15;
    int n = blockIdx.x * 4 + wv;
    if (n >= N) return;
    float acc[2][4] = {};

#pragma unroll
    for (int dir = 0; dir < 2; ++dir) {
        const int* ptr = dir == 0 ? rptr : cptr;
        const int* nbr = dir == 0 ? nbr_r : nbr_c;
        const float* invt = dir == 0 ? inv_in : inv_out;
        const unsigned char* zb = dir == 0 ? zs8 : zd8;
        int s = ptr[n], t = ptr[n + 1];
        for (int base = s; base < t; base += 64) {
            int cnt = t - base;
            if (cnt > 64) cnt = 64;
            int idx = 0;
            float ww = 0.f;
            if (lane < cnt) {
                idx = nbr[base + lane];
                ww = invt[idx];
            }
            for (int i = 0; i < cnt; i += 8) {
                int n0 = i + grp, n1 = i + 4 + grp;
                int c0 = __shfl(idx, n0, 64); float w0 = __shfl(ww, n0, 64);
                int c1 = __shfl(idx, n1, 64); float w1 = __shfl(ww, n1, 64);
                unsigned v0 = ((const unsigned*)(zb + (size_t)c0 * ZPAD))[sl];
                unsigned v1 = ((const unsigned*)(zb + (size_t)c1 * ZPAD))[sl];
                auto p00 = __builtin_amdgcn_cvt_pk_f32_fp8(v0, false);
                auto p01 = __builtin_amdgcn_cvt_pk_f32_fp8(v0, true);
                auto p10 = __builtin_amdgcn_cvt_pk_f32_fp8(v1, false);
                auto p11 = __builtin_amdgcn_cvt_pk_f32_fp8(v1, true);
                acc[dir][0] += w0 * p00[0] + w1 * p10[0];
                acc[dir][1] += w0 * p00[1] + w1 * p10[1];
                acc[dir][2] += w0 * p01[0] + w1 * p11[0];
                acc[dir][3] += w0 * p01[1] + w1 * p11[1];
            }
        }
    }

    float fac0 = 0.5f * inv_out[n], fac1 = 0.5f * inv_in[n];
    float a[4];
#pragma unroll
    for (int j = 0; j < 4; ++j) {
        a[j] = fac0 * acc[0][j] + fac1 * acc[1][j];
        a[j] += __shfl_xor(a[j], 16, 64);
        a[j] += __shfl_xor(a[j], 32, 64);
    }
    float val[4];
#pragma unroll
    for (int j = 0; j < 4; ++j) {
        int c = 4 * sl + j;
        val[j] = (c < CDIM) ? a[j] + 0.5f * (bs[c] + bd[c]) : -INFINITY;
    }
    float m = fmaxf(fmaxf(val[0], val[1]), fmaxf(val[2], val[3]));
    for (int off = 1; off < 16; off <<= 1) m = fmaxf(m, __shfl_xor(m, off, 64));
    float ex = 0.f;
#pragma unroll
    for (int j = 0; j < 4; ++j) ex += (4 * sl + j < CDIM) ? expf(val[j] - m) : 0.f;
    for (int off = 1; off < 16; off <<= 1) ex += __shfl_xor(ex, off, 64);
    float lse = logf(ex);
    if (grp == 0 && sl < 10) {
        float4 o;
        o.x = val[0] - m - lse;
        o.y = val[1] - m - lse;
        o.z = val[2] - m - lse;
        o.w = val[3] - m - lse;
        ((float4*)(out + (size_t)n * CDIM))[sl] = o;
    }
}

extern "C" void kernel_launch(void* const* d_in, const int* in_sizes, int n_in,
                              void* d_out, int out_size, void* d_ws, size_t ws_size,
                              hipStream_t stream) {
    const int N = in_sizes[0] / FDIM;
    const int E = in_sizes[1] / 2;
    const int NP = cdiv(N, NPAD_TO) * NPAD_TO;
    const int rpp = cdiv(N, NPART);

    const float* x = (const float*)d_in[0];
    const int* ei = (const int*)d_in[1];
    const int* row = ei;
    const int* col = ei + E;
    const float* ws1 = (const float*)d_in[2];
    const float* bs1 = (const float*)d_in[3];
    const float* wd1 = (const float*)d_in[4];
    const float* bd1 = (const float*)d_in[5];
    const float* ws2 = (const float*)d_in[6];
    const float* bs2 = (const float*)d_in[7];
    const float* wd2 = (const float*)d_in[8];
    const float* bd2 = (const float*)d_in[9];
    const float* ws3 = (const float*)d_in[10];
    const float* bs3 = (const float*)d_in[11];
    const float* wd3 = (const float*)d_in[12];
    const float* bd3 = (const float*)d_in[13];
    float* out = (float*)d_out;

    // ---- workspace carve ----
    char* base = (char*)d_ws;
    int* cnt_r = (int*)base;        base += sizeof(int) * N;
    int* cnt_c = (int*)base;        base += sizeof(int) * N;
    int* rptr = (int*)base;         base += sizeof(int) * (N + 1);
    int* cptr = (int*)base;         base += sizeof(int) * (N + 1);
    int* bsum = (int*)base;         base += sizeof(int) * 512;
    float* inv_out = (float*)base;  base += sizeof(float) * N;
    float* inv_in = (float*)base;   base += sizeof(float) * N;
    base = (char*)(((size_t)base + 15) & ~(size_t)15);
    int* blkcnt = (int*)base;       base += sizeof(int) * (size_t)2 * NPART * NBLK * rpp;
    int* nbr_r = (int*)base;        base += sizeof(int) * E;
    int* nbr_c = (int*)base;        base += sizeof(int) * E;
    base = (char*)(((size_t)base + 255) & ~(size_t)255);
    unsigned char* xb8 = (unsigned char*)base;  base += (size_t)NP * FDIM;
    base = (char*)(((size_t)base + 255) & ~(size_t)255);
    unsigned char* hb8 = (unsigned char*)base;  base += (size_t)NP * FDIM;
    base = (char*)(((size_t)base + 255) & ~(size_t)255);
    ushort* hb = (ushort*)base;     base += sizeof(ushort) * (size_t)NP * FDIM;
    ushort* aggb = (ushort*)base;   base += sizeof(ushort) * (size_t)NP * FDIM;
    ushort* aggtb = (ushort*)base;  base += sizeof(ushort) * (size_t)NP * FDIM;
    ushort* wbuf = (ushort*)base;   base += sizeof(ushort) * (4 * 65536 + 2 * 16384);
    unsigned char* zs8 = (unsigned char*)aggb;   // z aliases agg buffers (fp8, 64B rows)
    unsigned char* zd8 = (unsigned char*)aggtb;

    ushort* w1s = wbuf;
    ushort* w1d = wbuf + 65536;
    ushort* w2s = wbuf + 2 * 65536;
    ushort* w2d = wbuf + 3 * 65536;
    ushort* w3s = wbuf + 4 * 65536;
    ushort* w3d = wbuf + 4 * 65536 + 16384;

    const int nb = cdiv(N, 256);
    const int n4 = N * FDIM / 4;
    const int wn = 4 * 65536 + 2 * 16384;

    // ---- build: LDS-histogram count (+ casts fused), reduce, scans, atomic-free fill ----
    k_cnt<<<CNTB + cdiv(n4 + wn, 256), 256, 0, stream>>>(row, col, blkcnt, E, N,
                                                         x, n4, ws1, wd1, ws2, wd2, ws3, wd3,
                                                         xb8, wbuf);
    k_red<<<dim3(nb, 2), 256, 0, stream>>>(blkcnt, cnt_r, cnt_c, inv_out, inv_in, N);
    k_scan1<<<dim3(nb, 2), 256, 0, stream>>>(cnt_r, cnt_c, rptr, cptr, bsum, N);
    k_scan2<<<2, 256, 0, stream>>>(bsum, nb);
    k_scan3<<<dim3(nb, 2), 256, 0, stream>>>(rptr, cptr, bsum, N, E);
    k_fill2<<<CNTB, 256, 0, stream>>>(row, col, rptr, cptr, blkcnt, nbr_r, nbr_c, E, N);

    dim3 ggrid(cdiv(N, 4), 2);
    dim3 ggemm(NP / 64, 2);
    dim3 ggemm3(NP / 128, 1);

    // layer 1: gather(fp8 x) -> bf16 agg -> GEMM -> fp8 h
    k_gather_f8<<<ggrid, 256, 0, stream>>>(xb8, rptr, nbr_r, cptr, nbr_c, inv_out, inv_in, aggb, aggtb, N);
    k_gemm12<<<ggemm, 256, 0, stream>>>(aggb, aggtb, w1s, w1d, bs1, bd1, nullptr, hb8);

    // layer 2: gather(fp8 h) -> bf16 agg -> GEMM -> bf16 h (for gemm3)
    k_gather_f8<<<ggrid, 256, 0, stream>>>(hb8, rptr, nbr_r, cptr, nbr_c, inv_out, inv_in, aggb, aggtb, N);
    k_gemm12<<<ggemm, 256, 0, stream>>>(aggb, aggtb, w2s, w2d, bs2, bd2, hb, nullptr);

    // layer 3
    k_gemm3<<<ggemm3, 256, 0, stream>>>(hb, w3s, w3d, zs8, zd8);
    k_l3<<<cdiv(N, 4), 256, 0, stream>>>(zs8, zd8, rptr, nbr_r, cptr, nbr_c, inv_out, inv_in,
                                         bs3, bd3, out, N);
}

// Round 17
// 317.244 us; speedup vs baseline: 1.3367x; 1.0946x over previous
//
#include <hip/hip_runtime.h>
#include <math.h>

#define FDIM 256
#define CDIM 40
#define ZPAD 64
#define NPAD_TO 128
#define NPART 8
#define NBLK 64
#define CNTB (2 * NPART * NBLK)   // 1024 build blocks
#define PACKMAX 3200              // packed LDS capacity (2 counters/word); N <= NPART*2*PACKMAX

typedef __attribute__((ext_vector_type(8))) __bf16 bf16x8;
typedef __attribute__((ext_vector_type(4))) float f32x4;
typedef __attribute__((ext_vector_type(8))) ushort u16x8;
typedef __attribute__((ext_vector_type(4))) ushort u16x4;

static inline int cdiv(int a, int b) { return (a + b - 1) / b; }

__device__ __forceinline__ float b2f(ushort u) { return __uint_as_float(((unsigned)u) << 16); }
__device__ __forceinline__ ushort f2bf(float f) {
    unsigned u = __float_as_uint(f);
    unsigned r = (u + 0x7FFFu + ((u >> 16) & 1u)) >> 16;
    return (ushort)r;
}
__device__ __forceinline__ unsigned char f2fp8(float f) {
    int p = __builtin_amdgcn_cvt_pk_fp8_f32(f, f, 0, false);
    return (unsigned char)(p & 0xff);
}

__device__ __forceinline__ void gl_lds16(const void* gsrc, void* ldst) {
    __builtin_amdgcn_global_load_lds((const __attribute__((address_space(1))) unsigned*)gsrc,
                                     (__attribute__((address_space(3))) unsigned*)ldst, 16, 0, 0);
}

#define ACC8(v, w)                                                      \
    {                                                                   \
        auto p0 = __builtin_amdgcn_cvt_pk_f32_fp8((v).x, false);        \
        auto p1 = __builtin_amdgcn_cvt_pk_f32_fp8((v).x, true);         \
        auto p2 = __builtin_amdgcn_cvt_pk_f32_fp8((v).y, false);        \
        auto p3 = __builtin_amdgcn_cvt_pk_f32_fp8((v).y, true);         \
        a[0] += (w) * p0[0]; a[1] += (w) * p0[1];                       \
        a[2] += (w) * p1[0]; a[3] += (w) * p1[1];                       \
        a[4] += (w) * p2[0]; a[5] += (w) * p2[1];                       \
        a[6] += (w) * p3[0]; a[7] += (w) * p3[1];                       \
    }

// ---------------- pass 1: packed-LDS histogram count (no global atomics) + fused casts ----------------
// bid%8 = blk%8 -> all 16 (dir,part) blocks of one edge stripe share an XCD (stripe fetched 1x/XCD).
__global__ __launch_bounds__(256) void k_cnt(const int* __restrict__ row,
                                             const int* __restrict__ col,
                                             int* __restrict__ blkcnt, int E, int N,
                                             const float* __restrict__ x, int n4,
                                             const float* __restrict__ s1, const float* __restrict__ d1,
                                             const float* __restrict__ s2, const float* __restrict__ d2,
                                             const float* __restrict__ s3, const float* __restrict__ d3,
                                             unsigned char* __restrict__ xb8,
                                             ushort* __restrict__ wb) {
    int bid = blockIdx.x;
    if (bid < CNTB) {
        int dir = bid >> 9;            // NPART*NBLK = 512
        int rest = bid & 511;
        int part = rest >> 6;
        int blk = rest & 63;
        int rpp = (N + NPART - 1) / NPART;
        int lo = part * rpp;
        int hi = lo + rpp;
        if (hi > N) hi = N;
        __shared__ unsigned hist[PACKMAX];
        int np = (rpp + 1) >> 1;
        for (int i = threadIdx.x; i < np; i += 256) hist[i] = 0;
        __syncthreads();
        const int* key = dir ? col : row;
        int per = (E + NBLK - 1) / NBLK;
        int e0 = blk * per;
        int e1 = e0 + per;
        if (e1 > E) e1 = E;
        for (int e = e0 + threadIdx.x; e < e1; e += 256) {
            int k = key[e];
            if (k >= lo && k < hi) {
                int i = k - lo;
                atomicAdd(&hist[i >> 1], 1u << ((i & 1) * 16));
            }
        }
        __syncthreads();
        int* dst = blkcnt + ((size_t)(dir * NPART + part) * NBLK + blk) * rpp;
        for (int i = threadIdx.x; i < rpp; i += 256)
            dst[i] = (int)((hist[i >> 1] >> ((i & 1) * 16)) & 0xffffu);
        return;
    }
    int i = (bid - CNTB) * 256 + threadIdx.x;
    if (i < n4) {
        float4 v = ((const float4*)x)[i];
        uchar4 o;
        o.x = f2fp8(v.x); o.y = f2fp8(v.y); o.z = f2fp8(v.z); o.w = f2fp8(v.w);
        ((uchar4*)xb8)[i] = o;
        return;
    }
    int o = i - n4;
    const int BIG = 256 * 256;
    const int SM = 64 * 256;
    if (o >= 4 * BIG + 2 * SM) return;
    float v;
    if (o < BIG) v = s1[o];
    else if (o < 2 * BIG) v = d1[o - BIG];
    else if (o < 3 * BIG) v = s2[o - 2 * BIG];
    else if (o < 4 * BIG) v = d2[o - 3 * BIG];
    else {
        int oo = o - 4 * BIG;
        const float* src = (oo < SM) ? s3 : d3;
        oo = (oo < SM) ? oo : oo - SM;
        int r = oo >> 8;
        v = (r < CDIM) ? src[(r << 8) + (oo & 255)] : 0.0f;
    }
    wb[o] = f2bf(v);
}

// ---------------- reduce: per-node exclusive scan over 64 block counts (in place) + degree + inv ----
__global__ __launch_bounds__(256) void k_red(int* __restrict__ blkcnt,
                                             int* __restrict__ cnt_r,
                                             int* __restrict__ cnt_c,
                                             float* __restrict__ inv_out,
                                             float* __restrict__ inv_in, int N) {
    int dir = blockIdx.y;
    int n = blockIdx.x * 256 + threadIdx.x;
    if (n >= N) return;
    int rpp = (N + NPART - 1) / NPART;
    int part = n / rpp, i = n - part * rpp;
    int* p = blkcnt + ((size_t)(dir * NPART + part) * NBLK) * rpp + i;
    int s = 0;
#pragma unroll
    for (int b = 0; b < NBLK; ++b) {
        int v = p[(size_t)b * rpp];
        p[(size_t)b * rpp] = s;
        s += v;
    }
    float iv = s > 0 ? rsqrtf((float)s) : 0.0f;
    if (dir == 0) { cnt_r[n] = s; inv_out[n] = iv; }
    else          { cnt_c[n] = s; inv_in[n] = iv; }
}

// ---------------- fused r/c scan ----------------
__global__ __launch_bounds__(256) void k_scan1(const int* __restrict__ cnt_r,
                                               const int* __restrict__ cnt_c,
                                               int* __restrict__ rptr,
                                               int* __restrict__ cptr,
                                               int* __restrict__ bsum, int n) {
    const int* cnt = blockIdx.y ? cnt_c : cnt_r;
    int* ptr = blockIdx.y ? cptr : rptr;
    __shared__ int s[256];
    int t = threadIdx.x;
    int i = blockIdx.x * 256 + t;
    int v = (i < n) ? cnt[i] : 0;
    s[t] = v;
    __syncthreads();
    for (int off = 1; off < 256; off <<= 1) {
        int u = (t >= off) ? s[t - off] : 0;
        __syncthreads();
        s[t] += u;
        __syncthreads();
    }
    if (i < n) ptr[i] = s[t] - v;
    if (t == 255) bsum[blockIdx.y * 256 + blockIdx.x] = s[255];
}

__global__ __launch_bounds__(256) void k_scan2(int* __restrict__ bsum, int nb) {
    int* b = bsum + blockIdx.x * 256;
    __shared__ int s[256];
    int t = threadIdx.x;
    int v = (t < nb) ? b[t] : 0;
    s[t] = v;
    __syncthreads();
    for (int off = 1; off < 256; off <<= 1) {
        int u = (t >= off) ? s[t - off] : 0;
        __syncthreads();
        s[t] += u;
        __syncthreads();
    }
    if (t < nb) b[t] = s[t] - v;
}

__global__ __launch_bounds__(256) void k_scan3(int* __restrict__ rptr,
                                               int* __restrict__ cptr,
                                               const int* __restrict__ bsum,
                                               int n, int total) {
    int* ptr = blockIdx.y ? cptr : rptr;
    int i = blockIdx.x * 256 + threadIdx.x;
    if (i < n) ptr[i] += bsum[blockIdx.y * 256 + blockIdx.x];
    if (blockIdx.x == 0 && threadIdx.x == 0) ptr[n] = total;
}

// ---------------- pass 2: place entries via per-block offsets + packed LDS running counts ----------------
// part = bid&7 -> fixed bid%8 -> nbr stores XCD-local.
__global__ __launch_bounds__(256) void k_fill2(const int* __restrict__ row,
                                               const int* __restrict__ col,
                                               const int* __restrict__ rptr,
                                               const int* __restrict__ cptr,
                                               const int* __restrict__ blkoff,
                                               int* __restrict__ nbr_r,
                                               int* __restrict__ nbr_c,
                                               int E, int N) {
    int bid = blockIdx.x;              // 0..1023
    int part = bid & 7;
    int rest = bid >> 3;               // 0..127
    int dir = rest >> 6;
    int blk = rest & 63;
    int rpp = (N + NPART - 1) / NPART;
    int lo = part * rpp;
    int hi = lo + rpp;
    if (hi > N) hi = N;
    __shared__ unsigned used[PACKMAX];
    int np = (rpp + 1) >> 1;
    for (int i = threadIdx.x; i < np; i += 256) used[i] = 0;
    __syncthreads();
    const int* key = dir ? col : row;
    const int* val = dir ? row : col;
    const int* ptr = dir ? cptr : rptr;
    int* nbr = dir ? nbr_c : nbr_r;
    const int* off = blkoff + ((size_t)(dir * NPART + part) * NBLK + blk) * rpp;
    int per = (E + NBLK - 1) / NBLK;
    int e0 = blk * per;
    int e1 = e0 + per;
    if (e1 > E) e1 = E;
    for (int e = e0 + threadIdx.x; e < e1; e += 256) {
        int k = key[e];
        if (k >= lo && k < hi) {
            int i = k - lo;
            unsigned old = atomicAdd(&used[i >> 1], 1u << ((i & 1) * 16));
            int u = (int)((old >> ((i & 1) * 16)) & 0xffffu);
            nbr[ptr[k] + off[i] + u] = val[e];
        }
    }
}

// ---------------- fp8 gather: index-only adjacency + inv-table weights ----------------
__global__ __launch_bounds__(256) void k_gather_f8(const unsigned char* __restrict__ h8,
                                                   const int* __restrict__ rptr,
                                                   const int* __restrict__ nbr_r,
                                                   const int* __restrict__ cptr,
                                                   const int* __restrict__ nbr_c,
                                                   const float* __restrict__ inv_out,
                                                   const float* __restrict__ inv_in,
                                                   ushort* __restrict__ agg,
                                                   ushort* __restrict__ aggt, int N) {
    int wv = threadIdx.x >> 6, lane = threadIdx.x & 63;
    int half = lane >> 5, l32 = lane & 31;
    int n = blockIdx.x * 4 + wv;
    if (n >= N) return;
    const int* ptr;
    const int* nbr;
    const float* invt;
    float fac;
    ushort* out;
    if (blockIdx.y == 0) { ptr = rptr; nbr = nbr_r; invt = inv_in; fac = inv_out[n]; out = agg; }
    else                 { ptr = cptr; nbr = nbr_c; invt = inv_out; fac = inv_in[n]; out = aggt; }
    int s = ptr[n], t = ptr[n + 1];
    float a[8] = {};
    for (int base = s; base < t; base += 64) {
        int cnt = t - base;
        if (cnt > 64) cnt = 64;
        int idx = 0;
        float ww = 0.f;
        if (lane < cnt) {
            idx = nbr[base + lane];
            ww = invt[idx];
        }
        for (int i = 0; i < cnt; i += 8) {
            int n0 = i + half, n1 = i + 2 + half, n2 = i + 4 + half, n3 = i + 6 + half;
            int c0 = __shfl(idx, n0, 64); float w0 = __shfl(ww, n0, 64);
            int c1 = __shfl(idx, n1, 64); float w1 = __shfl(ww, n1, 64);
            int c2 = __shfl(idx, n2, 64); float w2 = __shfl(ww, n2, 64);
            int c3 = __shfl(idx, n3, 64); float w3 = __shfl(ww, n3, 64);
            uint2 v0 = ((const uint2*)(h8 + (size_t)c0 * FDIM))[l32];
            uint2 v1 = ((const uint2*)(h8 + (size_t)c1 * FDIM))[l32];
            uint2 v2 = ((const uint2*)(h8 + (size_t)c2 * FDIM))[l32];
            uint2 v3 = ((const uint2*)(h8 + (size_t)c3 * FDIM))[l32];
            ACC8(v0, w0);
            ACC8(v1, w1);
            ACC8(v2, w2);
            ACC8(v3, w3);
        }
    }
#pragma unroll
    for (int j = 0; j < 8; ++j) a[j] += __shfl_xor(a[j], 32, 64);
    if (half == 0) {
        u16x8 o;
#pragma unroll
        for (int j = 0; j < 8; ++j) o[j] = f2bf(a[j] * fac);
        ((u16x8*)(out + (size_t)n * FDIM))[l32] = o;
    }
}

// ---------------- MFMA dual GEMM layers 1-2: BM=64 x BN=128, dual-format epilogue ----------------
__global__ __launch_bounds__(256) void k_gemm12(const ushort* __restrict__ Ab,
                                                const ushort* __restrict__ Atb,
                                                const ushort* __restrict__ Wsb,
                                                const ushort* __restrict__ Wdb,
                                                const float* __restrict__ bs,
                                                const float* __restrict__ bd,
                                                ushort* __restrict__ outH,
                                                unsigned char* __restrict__ out8) {
    __shared__ char smA[8192];
    __shared__ char smAt[8192];
    __shared__ char smWs[16384];
    __shared__ char smWd[16384];

    const int tid = threadIdx.x;
    const int wv = tid >> 6, lane = tid & 63;
    const int n0 = blockIdx.x * 64;
    const int j0 = blockIdx.y * 128;

    const char* Abase = (const char*)Ab;
    const char* Atbase = (const char*)Atb;
    const char* Wsbase = (const char*)Wsb;
    const char* Wdbase = (const char*)Wdb;

    f32x4 accS[8] = {};
    f32x4 accD[8] = {};

    for (int k0 = 0; k0 < FDIM; k0 += 64) {
#pragma unroll
        for (int it = 0; it < 2; ++it) {
            int si = it * 256 + tid;
            int r = si >> 3, sl = si & 7;
            int gs = sl ^ (r & 7);
            size_t goff = (size_t)(n0 + r) * (FDIM * 2) + k0 * 2 + gs * 16;
            gl_lds16(Abase + goff, smA + si * 16);
            gl_lds16(Atbase + goff, smAt + si * 16);
        }
#pragma unroll
        for (int it = 0; it < 4; ++it) {
            int si = it * 256 + tid;
            int r = si >> 3, sl = si & 7;
            int gs = sl ^ (r & 7);
            size_t goff = (size_t)(j0 + r) * (FDIM * 2) + k0 * 2 + gs * 16;
            gl_lds16(Wsbase + goff, smWs + si * 16);
            gl_lds16(Wdbase + goff, smWd + si * 16);
        }
        __syncthreads();
#pragma unroll
        for (int kh = 0; kh < 2; ++kh) {
            int rA = wv * 16 + (lane & 15);
            int sA = (kh * 4 + (lane >> 4)) ^ (rA & 7);
            bf16x8 aS = *(const bf16x8*)(smA + rA * 128 + sA * 16);
            bf16x8 aT = *(const bf16x8*)(smAt + rA * 128 + sA * 16);
#pragma unroll
            for (int ni = 0; ni < 8; ++ni) {
                int rB = ni * 16 + (lane & 15);
                int sB = (kh * 4 + (lane >> 4)) ^ (rB & 7);
                bf16x8 bSv = *(const bf16x8*)(smWs + rB * 128 + sB * 16);
                bf16x8 bDv = *(const bf16x8*)(smWd + rB * 128 + sB * 16);
                accS[ni] = __builtin_amdgcn_mfma_f32_16x16x32_bf16(aS, bSv, accS[ni], 0, 0, 0);
                accD[ni] = __builtin_amdgcn_mfma_f32_16x16x32_bf16(aT, bDv, accD[ni], 0, 0, 0);
            }
        }
        __syncthreads();
    }

#pragma unroll
    for (int ni = 0; ni < 8; ++ni) {
        int j = j0 + ni * 16 + (lane & 15);
        float bsv = bs[j], bdv = bd[j];
#pragma unroll
        for (int r = 0; r < 4; ++r) {
            int n = n0 + wv * 16 + (lane >> 4) * 4 + r;
            float v = 0.5f * (accS[ni][r] + bsv) + 0.5f * (accD[ni][r] + bdv);
            v = fmaxf(v, 0.0f);
            if (out8) out8[(size_t)n * FDIM + j] = f2fp8(v);
            else outH[(size_t)n * FDIM + j] = f2bf(v);
        }
    }
}

// ---------------- MFMA layer-3 GEMM: zs/zd as fp8 padded to 64 cols ----------------
__global__ __launch_bounds__(256) void k_gemm3(const ushort* __restrict__ Hb,
                                               const ushort* __restrict__ Wsb,
                                               const ushort* __restrict__ Wdb,
                                               unsigned char* __restrict__ zs8,
                                               unsigned char* __restrict__ zd8) {
    __shared__ char smA[16384];
    __shared__ char smWs[8192];
    __shared__ char smWd[8192];

    const int tid = threadIdx.x;
    const int wv = tid >> 6, lane = tid & 63;
    const int n0 = blockIdx.x * 128;

    const char* Abase = (const char*)Hb;
    const char* Wsbase = (const char*)Wsb;
    const char* Wdbase = (const char*)Wdb;

    f32x4 accS[2][4] = {};
    f32x4 accD[2][4] = {};

    for (int k0 = 0; k0 < FDIM; k0 += 64) {
#pragma unroll
        for (int it = 0; it < 4; ++it) {
            int si = (wv * 4 + it) * 64 + lane;
            int r = si >> 3, sl = si & 7;
            int gs = sl ^ (r & 7);
            size_t goff = (size_t)(n0 + r) * (FDIM * 2) + k0 * 2 + gs * 16;
            gl_lds16(Abase + goff, smA + si * 16);
        }
#pragma unroll
        for (int it = 0; it < 2; ++it) {
            int si = (wv * 2 + it) * 64 + lane;
            int r = si >> 3, sl = si & 7;
            int gs = sl ^ (r & 7);
            size_t goff = (size_t)r * (FDIM * 2) + k0 * 2 + gs * 16;
            gl_lds16(Wsbase + goff, smWs + si * 16);
            gl_lds16(Wdbase + goff, smWd + si * 16);
        }
        __syncthreads();
#pragma unroll
        for (int kh = 0; kh < 2; ++kh) {
            bf16x8 aS[2], bS[4], bD[4];
#pragma unroll
            for (int mi = 0; mi < 2; ++mi) {
                int r = wv * 32 + mi * 16 + (lane & 15);
                int off = r * 128 + (((kh * 4 + (lane >> 4)) ^ (r & 7)) * 16);
                aS[mi] = *(const bf16x8*)(smA + off);
            }
#pragma unroll
            for (int ni = 0; ni < 4; ++ni) {
                int r = ni * 16 + (lane & 15);
                int off = r * 128 + (((kh * 4 + (lane >> 4)) ^ (r & 7)) * 16);
                bS[ni] = *(const bf16x8*)(smWs + off);
                bD[ni] = *(const bf16x8*)(smWd + off);
            }
#pragma unroll
            for (int mi = 0; mi < 2; ++mi)
#pragma unroll
                for (int ni = 0; ni < 4; ++ni) {
                    accS[mi][ni] = __builtin_amdgcn_mfma_f32_16x16x32_bf16(aS[mi], bS[ni], accS[mi][ni], 0, 0, 0);
                    accD[mi][ni] = __builtin_amdgcn_mfma_f32_16x16x32_bf16(aS[mi], bD[ni], accD[mi][ni], 0, 0, 0);
                }
        }
        __syncthreads();
    }

#pragma unroll
    for (int mi = 0; mi < 2; ++mi)
#pragma unroll
        for (int ni = 0; ni < 4; ++ni) {
            int j = ni * 16 + (lane & 15);
            f32x4 cs = accS[mi][ni], cd = accD[mi][ni];
#pragma unroll
            for (int r = 0; r < 4; ++r) {
                int n = n0 + wv * 32 + mi * 16 + (lane >> 4) * 4 + r;
                zs8[(size_t)n * ZPAD + j] = f2fp8(cs[r]);
                zd8[(size_t)n * ZPAD + j] = f2fp8(cd[r]);
            }
        }
}

// ---------------- layer 3: gather over fp8 z + inv-table weights + log_softmax ----------------
__global__ __launch_bounds__(256) void k_l3(const unsigned char* __restrict__ zs8,
                                            const unsigned char* __restrict__ zd8,
                                            const int* __restrict__ rptr,
                                            const int* __restrict__ nbr_r,
                                            const int* __restrict__ cptr,
                                            const int* __restrict__ nbr_c,
                                            const float* __restrict__ inv_out,
                                            const float* __restrict__ inv_in,
                                            const float* __restrict__ bs,
                                            const float* __restrict__ bd,
                                            float* __restrict__ out, int N) {
    int wv = threadIdx.x >> 6, lane = threadIdx.x & 63;
    int grp = lane >> 4, sl = lane & 15;
    int n = blockIdx.x * 4 + wv;
    if (n >= N) return;
    float acc[2][4] = {};

#pragma unroll
    for (int dir = 0; dir < 2; ++dir) {
        const int* ptr = dir == 0 ? rptr : cptr;
        const int* nbr = dir == 0 ? nbr_r : nbr_c;
        const float* invt = dir == 0 ? inv_in : inv_out;
        const unsigned char* zb = dir == 0 ? zs8 : zd8;
        int s = ptr[n], t = ptr[n + 1];
        for (int base = s; base < t; base += 64) {
            int cnt = t - base;
            if (cnt > 64) cnt = 64;
            int idx = 0;
            float ww = 0.f;
            if (lane < cnt) {
                idx = nbr[base + lane];
                ww = invt[idx];
            }
            for (int i = 0; i < cnt; i += 8) {
                int n0 = i + grp, n1 = i + 4 + grp;
                int c0 = __shfl(idx, n0, 64); float w0 = __shfl(ww, n0, 64);
                int c1 = __shfl(idx, n1, 64); float w1 = __shfl(ww, n1, 64);
                unsigned v0 = ((const unsigned*)(zb + (size_t)c0 * ZPAD))[sl];
                unsigned v1 = ((const unsigned*)(zb + (size_t)c1 * ZPAD))[sl];
                auto p00 = __builtin_amdgcn_cvt_pk_f32_fp8(v0, false);
                auto p01 = __builtin_amdgcn_cvt_pk_f32_fp8(v0, true);
                auto p10 = __builtin_amdgcn_cvt_pk_f32_fp8(v1, false);
                auto p11 = __builtin_amdgcn_cvt_pk_f32_fp8(v1, true);
                acc[dir][0] += w0 * p00[0] + w1 * p10[0];
                acc[dir][1] += w0 * p00[1] + w1 * p10[1];
                acc[dir][2] += w0 * p01[0] + w1 * p11[0];
                acc[dir][3] += w0 * p01[1] + w1 * p11[1];
            }
        }
    }

    float fac0 = 0.5f * inv_out[n], fac1 = 0.5f * inv_in[n];
    float a[4];
#pragma unroll
    for (int j = 0; j < 4; ++j) {
        a[j] = fac0 * acc[0][j] + fac1 * acc[1][j];
        a[j] += __shfl_xor(a[j], 16, 64);
        a[j] += __shfl_xor(a[j], 32, 64);
    }
    float val[4];
#pragma unroll
    for (int j = 0; j < 4; ++j) {
        int c = 4 * sl + j;
        val[j] = (c < CDIM) ? a[j] + 0.5f * (bs[c] + bd[c]) : -INFINITY;
    }
    float m = fmaxf(fmaxf(val[0], val[1]), fmaxf(val[2], val[3]));
    for (int off = 1; off < 16; off <<= 1) m = fmaxf(m, __shfl_xor(m, off, 64));
    float ex = 0.f;
#pragma unroll
    for (int j = 0; j < 4; ++j) ex += (4 * sl + j < CDIM) ? expf(val[j] - m) : 0.f;
    for (int off = 1; off < 16; off <<= 1) ex += __shfl_xor(ex, off, 64);
    float lse = logf(ex);
    if (grp == 0 && sl < 10) {
        float4 o;
        o.x = val[0] - m - lse;
        o.y = val[1] - m - lse;
        o.z = val[2] - m - lse;
        o.w = val[3] - m - lse;
        ((float4*)(out + (size_t)n * CDIM))[sl] = o;
    }
}

extern "C" void kernel_launch(void* const* d_in, const int* in_sizes, int n_in,
                              void* d_out, int out_size, void* d_ws, size_t ws_size,
                              hipStream_t stream) {
    const int N = in_sizes[0] / FDIM;
    const int E = in_sizes[1] / 2;
    const int NP = cdiv(N, NPAD_TO) * NPAD_TO;
    const int rpp = cdiv(N, NPART);

    const float* x = (const float*)d_in[0];
    const int* ei = (const int*)d_in[1];
    const int* row = ei;
    const int* col = ei + E;
    const float* ws1 = (const float*)d_in[2];
    const float* bs1 = (const float*)d_in[3];
    const float* wd1 = (const float*)d_in[4];
    const float* bd1 = (const float*)d_in[5];
    const float* ws2 = (const float*)d_in[6];
    const float* bs2 = (const float*)d_in[7];
    const float* wd2 = (const float*)d_in[8];
    const float* bd2 = (const float*)d_in[9];
    const float* ws3 = (const float*)d_in[10];
    const float* bs3 = (const float*)d_in[11];
    const float* wd3 = (const float*)d_in[12];
    const float* bd3 = (const float*)d_in[13];
    float* out = (float*)d_out;

    // ---- workspace carve ----
    char* base = (char*)d_ws;
    int* cnt_r = (int*)base;        base += sizeof(int) * N;
    int* cnt_c = (int*)base;        base += sizeof(int) * N;
    int* rptr = (int*)base;         base += sizeof(int) * (N + 1);
    int* cptr = (int*)base;         base += sizeof(int) * (N + 1);
    int* bsum = (int*)base;         base += sizeof(int) * 512;
    float* inv_out = (float*)base;  base += sizeof(float) * N;
    float* inv_in = (float*)base;   base += sizeof(float) * N;
    base = (char*)(((size_t)base + 15) & ~(size_t)15);
    int* blkcnt = (int*)base;       base += sizeof(int) * (size_t)2 * NPART * NBLK * rpp;
    int* nbr_r = (int*)base;        base += sizeof(int) * E;
    int* nbr_c = (int*)base;        base += sizeof(int) * E;
    base = (char*)(((size_t)base + 255) & ~(size_t)255);
    unsigned char* xb8 = (unsigned char*)base;  base += (size_t)NP * FDIM;
    base = (char*)(((size_t)base + 255) & ~(size_t)255);
    unsigned char* hb8 = (unsigned char*)base;  base += (size_t)NP * FDIM;
    base = (char*)(((size_t)base + 255) & ~(size_t)255);
    ushort* hb = (ushort*)base;     base += sizeof(ushort) * (size_t)NP * FDIM;
    ushort* aggb = (ushort*)base;   base += sizeof(ushort) * (size_t)NP * FDIM;
    ushort* aggtb = (ushort*)base;  base += sizeof(ushort) * (size_t)NP * FDIM;
    ushort* wbuf = (ushort*)base;   base += sizeof(ushort) * (4 * 65536 + 2 * 16384);
    unsigned char* zs8 = (unsigned char*)aggb;   // z aliases agg buffers (fp8, 64B rows)
    unsigned char* zd8 = (unsigned char*)aggtb;

    ushort* w1s = wbuf;
    ushort* w1d = wbuf + 65536;
    ushort* w2s = wbuf + 2 * 65536;
    ushort* w2d = wbuf + 3 * 65536;
    ushort* w3s = wbuf + 4 * 65536;
    ushort* w3d = wbuf + 4 * 65536 + 16384;

    const int nb = cdiv(N, 256);
    const int n4 = N * FDIM / 4;
    const int wn = 4 * 65536 + 2 * 16384;

    // ---- build: packed-LDS histogram count (+ casts fused), reduce, scans, atomic-free fill ----
    k_cnt<<<CNTB + cdiv(n4 + wn, 256), 256, 0, stream>>>(row, col, blkcnt, E, N,
                                                         x, n4, ws1, wd1, ws2, wd2, ws3, wd3,
                                                         xb8, wbuf);
    k_red<<<dim3(nb, 2), 256, 0, stream>>>(blkcnt, cnt_r, cnt_c, inv_out, inv_in, N);
    k_scan1<<<dim3(nb, 2), 256, 0, stream>>>(cnt_r, cnt_c, rptr, cptr, bsum, N);
    k_scan2<<<2, 256, 0, stream>>>(bsum, nb);
    k_scan3<<<dim3(nb, 2), 256, 0, stream>>>(rptr, cptr, bsum, N, E);
    k_fill2<<<CNTB, 256, 0, stream>>>(row, col, rptr, cptr, blkcnt, nbr_r, nbr_c, E, N);

    dim3 ggrid(cdiv(N, 4), 2);
    dim3 ggemm(NP / 64, 2);
    dim3 ggemm3(NP / 128, 1);

    // layer 1: gather(fp8 x) -> bf16 agg -> GEMM -> fp8 h
    k_gather_f8<<<ggrid, 256, 0, stream>>>(xb8, rptr, nbr_r, cptr, nbr_c, inv_out, inv_in, aggb, aggtb, N);
    k_gemm12<<<ggemm, 256, 0, stream>>>(aggb, aggtb, w1s, w1d, bs1, bd1, nullptr, hb8);

    // layer 2: gather(fp8 h) -> bf16 agg -> GEMM -> bf16 h (for gemm3)
    k_gather_f8<<<ggrid, 256, 0, stream>>>(hb8, rptr, nbr_r, cptr, nbr_c, inv_out, inv_in, aggb, aggtb, N);
    k_gemm12<<<ggemm, 256, 0, stream>>>(aggb, aggtb, w2s, w2d, bs2, bd2, hb, nullptr);

    // layer 3
    k_gemm3<<<ggemm3, 256, 0, stream>>>(hb, w3s, w3d, zs8, zd8);
    k_l3<<<cdiv(N, 4), 256, 0, stream>>>(zs8, zd8, rptr, nbr_r, cptr, nbr_c, inv_out, inv_in,
                                         bs3, bd3, out, N);
}